// Round 11
// baseline (103.885 us; speedup 1.0000x reference)
//
#include <hip/hip_runtime.h>
#include <hip/hip_bf16.h>
#include <math.h>

// Transformer-XL relative multi-head attention, bf16 MFMA implementation.
// B=4, S=1024, H=16, Dh=32, DIM=512.
//
// relative_shift identity: shifted[q,k] = qv[q]·pA[m] + qv[q+1]·pB[m],
// m = k - q + S - 1;  pA[m]=Z[S+1+m], pB[m]=Z[m] with a single zero-padded
// tensor Z (rows [S+1, 2S+1) = p, all else 0).
//
// Round 11: counted-vmcnt software pipeline (guide T3/T4). R9/R10 showed
// ~73% of each attn iteration is exposed in-body latency (Z loads consumed
// on-chain + vmcnt(0) barrier drain). Changes:
//  * attn: Z-window prefetched 1 iter ahead in registers (copy at body end
//    is the wait point -> full-body slack); K/V staged 2 tiles ahead into
//    4 LDS buffers; raw s_barrier preceded by asm vmcnt(1) (stage stays in
//    flight across the barrier); sched_barrier(0) pins stage after Z loads;
//    row-sums via ones-MFMA on the already-loaded P fragment.
//  * gemm: BK=32, 4 LDS buffers, stage 2 ahead, ONE barrier/iter + vmcnt(4).

typedef float f32x4 __attribute__((ext_vector_type(4)));
typedef __bf16 bf16x8 __attribute__((ext_vector_type(8)));
typedef __bf16 bf16x2 __attribute__((ext_vector_type(2)));

#define MFMA16(a, b, c) __builtin_amdgcn_mfma_f32_16x16x32_bf16((a), (b), (c), 0, 0, 0)

constexpr int Bb  = 4;
constexpr int S   = 1024;
constexpr int H   = 16;
constexpr int Dh  = 32;
constexpr int DIM = 512;
constexpr float SCALE = 0.17677669529663687f;  // 1/sqrt(32)
constexpr int ZROWS = 3 * S + 16;              // phZ rows per (b,h)

constexpr size_t XN = (size_t)Bb * S * DIM;   // elems per activation tensor
constexpr size_t WN = (size_t)DIM * DIM;      // elems per weight matrix

__device__ inline bf16x8 cvt8(const float* __restrict__ p) {
  f32x4 a = *(const f32x4*)p;
  f32x4 b = *(const f32x4*)(p + 4);
  bf16x8 r;
  r[0] = (__bf16)a[0]; r[1] = (__bf16)a[1]; r[2] = (__bf16)a[2]; r[3] = (__bf16)a[3];
  r[4] = (__bf16)b[0]; r[5] = (__bf16)b[1]; r[6] = (__bf16)b[2]; r[7] = (__bf16)b[3];
  return r;
}

__device__ inline void gload_lds16(const __bf16* g, __bf16* l) {
  __builtin_amdgcn_global_load_lds(
      (const __attribute__((address_space(1))) unsigned int*)g,
      (__attribute__((address_space(3))) unsigned int*)l, 16, 0, 0);
}

// ---------------------------------------------------------------------------
// Kernel 0: f32 -> bf16 conversion of activations (y=0..3) and weights (y=4..8).
// ---------------------------------------------------------------------------
__global__ __launch_bounds__(256) void conv_kernel(
    const float* __restrict__ q, const float* __restrict__ k,
    const float* __restrict__ v, const float* __restrict__ p,
    const float* __restrict__ wq, const float* __restrict__ wk,
    const float* __restrict__ wv, const float* __restrict__ wp,
    const float* __restrict__ wo,
    __bf16* __restrict__ xb, __bf16* __restrict__ wb)
{
  const int y = blockIdx.y;
  const float* src;
  size_t n;
  __bf16* dst;
  if (y < 4) {
    src = (y == 0) ? q : (y == 1) ? k : (y == 2) ? v : p;
    n = XN;
    dst = xb + (size_t)y * XN;
  } else {
    const int w = y - 4;
    src = (w == 0) ? wq : (w == 1) ? wk : (w == 2) ? wv : (w == 3) ? wp : wo;
    n = WN;
    dst = wb + (size_t)w * WN;
  }
  const size_t i = ((size_t)blockIdx.x * 256 + threadIdx.x) * 8;
  if (i >= n) return;
  *(bf16x8*)(dst + i) = cvt8(src + i);
}

// ---------------------------------------------------------------------------
// Kernel 1: tiled bf16 GEMM  C[M, N=512] = A @ B^T, K=512.
// 128x128 tile, BK=32, 4 waves, 4 LDS buffers, stage 2 tiles ahead with
// global_load_lds(16B); ONE raw barrier per iter preceded by vmcnt(4) —
// the newest 4 staging loads stay in flight across the barrier.
// mode 0: z=0..3 projections; mode 1: z=4 outproj (f32 + bo).
// ---------------------------------------------------------------------------
__global__ __launch_bounds__(256) void gemm_kernel(
    const __bf16* __restrict__ xb, const __bf16* __restrict__ wb,
    const __bf16* __restrict__ ctxp,
    const float* __restrict__ bq, const float* __restrict__ bk,
    const float* __restrict__ bv, const float* __restrict__ bo,
    const float* __restrict__ ub, const float* __restrict__ vb,
    __bf16* __restrict__ qu, __bf16* __restrict__ qv,
    __bf16* __restrict__ kk, __bf16* __restrict__ vt,
    __bf16* __restrict__ phZ,
    float* __restrict__ outp, int mode)
{
  __shared__ __align__(16) __bf16 As[4][128 * 32];
  __shared__ __align__(16) __bf16 Bs[4][128 * 32];

  const int bid = blockIdx.x;
  const int u = bid >> 3;
  const int by = u & 3;
  const int idx = (bid & 7) + 8 * (u >> 2);
  int bx, z;
  if (mode == 0) { bx = idx & 31; z = idx >> 5; }
  else           { bx = idx;      z = 4; }

  const __bf16* Ag = (z < 4) ? (xb + (size_t)z * XN) : ctxp;
  const __bf16* Bg = wb + (size_t)z * WN;

  const int tid = threadIdx.x;
  const int wid = tid >> 6;
  const int ln = tid & 63;
  const int lm = ln & 15, lg = ln >> 4;
  const int wr = wid >> 1, wc = wid & 1;
  const int brow = bx * 128;
  const int bcol = by * 128;

  // staging lane roles: 16 rows x 4 chunks of 8 per gload (1KB).
  const int srow = ln >> 2;                          // 0..15
  const int scg  = ((ln & 3) ^ (srow & 3)) * 8;      // inverse-swizzled chunk

  // wave stages A rows [wid*32, wid*32+32) and B rows likewise: 4 gloads.
  auto stage = [&](int kt, int buf) {
    const int k0 = kt * 32;
#pragma unroll
    for (int g = 0; g < 2; ++g) {
      const int rb = wid * 32 + g * 16;
      gload_lds16(Ag + (size_t)(brow + rb + srow) * DIM + k0 + scg,
                  &As[buf][rb * 32]);
      gload_lds16(Bg + (size_t)(bcol + rb + srow) * DIM + k0 + scg,
                  &Bs[buf][rb * 32]);
    }
  };

  f32x4 acc[4][4] = {};
  const int NT = DIM / 32;   // 16 k-tiles

  stage(0, 0);
  stage(1, 1);
  asm volatile("s_waitcnt vmcnt(4)" ::: "memory");
  __builtin_amdgcn_s_barrier();

  for (int t = 0; t < NT; ++t) {
    const int tn = (t + 2 < NT) ? t + 2 : t;   // clamped re-stage keeps counts
    stage(tn, (t + 2) & 3);

    const __bf16* Ab = As[t & 3];
    const __bf16* Bb2 = Bs[t & 3];
    bf16x8 a[4], b[4];
#pragma unroll
    for (int m = 0; m < 4; ++m) {
      const int row = wr * 64 + m * 16 + lm;
      a[m] = *(const bf16x8*)&Ab[row * 32 + (lg ^ (row & 3)) * 8];
    }
#pragma unroll
    for (int n = 0; n < 4; ++n) {
      const int row = wc * 64 + n * 16 + lm;
      b[n] = *(const bf16x8*)&Bb2[row * 32 + (lg ^ (row & 3)) * 8];
    }
#pragma unroll
    for (int m = 0; m < 4; ++m)
#pragma unroll
      for (int n = 0; n < 4; ++n)
        acc[m][n] = MFMA16(a[m], b[n], acc[m][n]);

    asm volatile("s_waitcnt vmcnt(4)" ::: "memory");
    __builtin_amdgcn_s_barrier();
  }

  // ---- epilogue
#pragma unroll
  for (int n = 0; n < 4; ++n) {
    const int o = bcol + wc * 64 + n * 16 + lm;
    float bias = 0.f, ubv = 0.f, vbv = 0.f;
    if (z == 0) { bias = bq[o]; ubv = ub[o]; vbv = vb[o]; }
    else if (z == 1) bias = bk[o];
    else if (z == 2) bias = bv[o];
    else if (z == 4) bias = bo[o];
    const int h = o >> 5, d = o & 31;
#pragma unroll
    for (int m = 0; m < 4; ++m) {
#pragma unroll
      for (int r = 0; r < 4; ++r) {
        const int M = brow + wr * 64 + m * 16 + lg * 4 + r;
        const float val = acc[m][n][r];
        if (z == 4) {
          outp[(size_t)M * DIM + o] = val + bias;
          continue;
        }
        const int b = M >> 10, s = M & (S - 1);
        const int bh = b * H + h;
        if (z == 0) {
          // 1/sqrt(Dh) folded in here (scores use pre-scaled q).
          const size_t idx2 = ((size_t)bh * S + s) * Dh + d;
          qu[idx2] = (__bf16)((val + bias + ubv) * SCALE);
          qv[idx2] = (__bf16)((val + bias + vbv) * SCALE);
        } else if (z == 1) {
          kk[((size_t)bh * S + s) * Dh + d] = (__bf16)(val + bias);
        } else if (z == 2) {
          // V^T with k-interleaved columns within each 32-block:
          // pos(t) = 2t (t<16) else 2t-31 -> matches attn's packed P stores.
          const int t2 = s & 31;
          const int sp = (s & ~31) | ((t2 < 16) ? (t2 << 1) : ((t2 << 1) - 31));
          vt[((size_t)bh * Dh + d) * S + sp] = (__bf16)(val + bias);
        } else {
          // phZ rows [S+1, 2S+1) = p; everything else pre-zeroed by memset.
          phZ[((size_t)bh * ZROWS + (S + 1 + s)) * Dh + d] = (__bf16)val;
        }
      }
    }
  }
}

// ---------------------------------------------------------------------------
// Kernel 2: fused attention. 256-thread blocks, 4 waves x 32 q-rows. K/V
// staged 2 tiles ahead in 4 LDS buffers (XOR-swizzled); Z-window prefetched
// 1 iter ahead in registers; raw s_barrier + counted vmcnt(1); row sums via
// ones-MFMA; max-free softmax; pos diagonal gather via __shfl.
// ---------------------------------------------------------------------------
__global__ __launch_bounds__(256, 2) void attn_kernel(
    const __bf16* __restrict__ qu, const __bf16* __restrict__ qv,
    const __bf16* __restrict__ kk, const __bf16* __restrict__ vt,
    const __bf16* __restrict__ phZ,
    __bf16* __restrict__ ctx)
{
  __shared__ __align__(16) __bf16 kv_lds[4][2][1024];  // [buf][K|V][32x32]
  __shared__ __align__(16) __bf16 at_all[4][32 * 40];

  const int tid = threadIdx.x;
  const int wid = tid >> 6;
  const int l = tid & 63;
  const int lm = l & 15, lg = l >> 4;

  const int bid = blockIdx.x;               // [0, 512)
  const int bh = (bid & 7) + 8 * ((bid >> 3) & 7);  // bh resident on XCD bid&7
  const int q0 = (bid >> 6) * 128 + wid * 32;
  const int h = bh & (H - 1), b = bh >> 4;

  const __bf16* qub = qu + (size_t)bh * S * Dh;
  const __bf16* qvb = qv + (size_t)bh * S * Dh;
  const __bf16* kb  = kk + (size_t)bh * S * Dh;
  const __bf16* vtb = vt + (size_t)bh * Dh * S;
  const __bf16* pZb = phZ + (size_t)bh * ZROWS * Dh;
  const __bf16* pAb = pZb + (size_t)(S + 1) * Dh;   // pA[m] = Z[S+1+m]

  const bf16x8 au0  = *(const bf16x8*)(qub + (size_t)(q0 + lm) * Dh + lg * 8);
  const bf16x8 au1  = *(const bf16x8*)(qub + (size_t)(q0 + 16 + lm) * Dh + lg * 8);
  const bf16x8 avA0 = *(const bf16x8*)(qvb + (size_t)(q0 + lm) * Dh + lg * 8);
  const bf16x8 avA1 = *(const bf16x8*)(qvb + (size_t)(q0 + 16 + lm) * Dh + lg * 8);
  // rows q+1 for the pB term; one-past reads hit allocated memory and are
  // multiplied by pB rows that are exactly zero wherever consumed.
  const bf16x8 avB0 = *(const bf16x8*)(qvb + (size_t)(q0 + 1 + lm) * Dh + lg * 8);
  const bf16x8 avB1 = *(const bf16x8*)(qvb + (size_t)(q0 + 17 + lm) * Dh + lg * 8);

  int  slr[4];
  bool prd[4];
#pragma unroll
  for (int r = 0; r < 4; ++r) {
    const int qr = lg * 4 + r;
    slr[r] = (l & 48) | ((lm - qr + 15) & 15);
    prd[r] = (lm <= qr);
  }

  bf16x8 ones8;
#pragma unroll
  for (int i = 0; i < 8; ++i) ones8[i] = (__bf16)1.0f;

  f32x4 ca0 = {0.f,0.f,0.f,0.f}, cb0 = {0.f,0.f,0.f,0.f};
  f32x4 ca1 = {0.f,0.f,0.f,0.f}, cb1 = {0.f,0.f,0.f,0.f};
  f32x4 ls0 = {0.f,0.f,0.f,0.f}, ls1 = {0.f,0.f,0.f,0.f};
  const f32x4 zero4 = {0.f,0.f,0.f,0.f};

  const int srow = l >> 2;
  const int scg  = ((l & 3) ^ (srow & 3)) * 8;
  auto stage = [&](int kt, int buf) {
    const __bf16* src;
    if (wid == 0)      src = kb  + (size_t)(kt + srow) * Dh + scg;
    else if (wid == 1) src = kb  + (size_t)(kt + 16 + srow) * Dh + scg;
    else if (wid == 2) src = vtb + (size_t)srow * S + kt + scg;
    else               src = vtb + (size_t)(16 + srow) * S + kt + scg;
    gload_lds16(src, &kv_lds[buf][wid >> 1][(wid & 1) * 512]);
  };

  const int cc = (lg ^ (lm & 3)) * 8;
  __bf16* at = at_all[wid];

  // ---- prologue: Z window for tile 0 + stage tiles 0,1
  bool useBc = (0 >= q0);
  {
    const int mb = 0 - q0 + (S - 32);
    const __bf16* zb = useBc ? pZb : pAb;
    // loads below fill zc0..zc3
  }
  int mbc = 0 - q0 + (S - 32);
  const __bf16* zbc = useBc ? pZb : pAb;
  bf16x8 zc0 = *(const bf16x8*)(zbc + (size_t)(mbc + lm) * Dh + lg * 8);
  bf16x8 zc1 = *(const bf16x8*)(zbc + (size_t)(mbc + 16 + lm) * Dh + lg * 8);
  bf16x8 zc2 = *(const bf16x8*)(zbc + (size_t)(mbc + 32 + lm) * Dh + lg * 8);
  bf16x8 zc3 = *(const bf16x8*)(zbc + (size_t)(mbc + 48 + lm) * Dh + lg * 8);

  stage(0, 0);
  stage(32, 1);
  asm volatile("s_waitcnt vmcnt(1)" ::: "memory");
  __builtin_amdgcn_s_barrier();

  for (int kt = 0; kt < S; kt += 32) {
    const int tb = (kt >> 5) & 3;

    // ---- prefetch next tile's Z window into registers (consumed next iter)
    const int kt2 = (kt + 32 < S) ? kt + 32 : kt;
    const bool useBn = (kt2 >= q0);
    const int mbn = kt2 - q0 + (S - 32);
    const __bf16* zbn = useBn ? pZb : pAb;
    bf16x8 zn0 = *(const bf16x8*)(zbn + (size_t)(mbn + lm) * Dh + lg * 8);
    bf16x8 zn1 = *(const bf16x8*)(zbn + (size_t)(mbn + 16 + lm) * Dh + lg * 8);
    bf16x8 zn2 = *(const bf16x8*)(zbn + (size_t)(mbn + 32 + lm) * Dh + lg * 8);
    bf16x8 zn3 = *(const bf16x8*)(zbn + (size_t)(mbn + 48 + lm) * Dh + lg * 8);

    // ---- content scores from LDS K
    const __bf16* Ks = kv_lds[tb][0];
    const __bf16* Vs = kv_lds[tb][1];
    bf16x8 kf0 = *(const bf16x8*)(Ks + lm * 32 + cc);
    bf16x8 kf1 = *(const bf16x8*)(Ks + (lm + 16) * 32 + cc);
    f32x4 c00 = MFMA16(au0, kf0, zero4);
    f32x4 c10 = MFMA16(au0, kf1, zero4);
    f32x4 c01 = MFMA16(au1, kf0, zero4);
    f32x4 c11 = MFMA16(au1, kf1, zero4);

    // ---- positional scores from prefetched Z registers
    const bf16x8 av0 = useBc ? avB0 : avA0;
    const bf16x8 av1 = useBc ? avB1 : avA1;
    f32x4 p0h1 = MFMA16(av1, zc0, zero4);
    f32x4 p1h1 = MFMA16(av1, zc1, zero4);
    f32x4 p2h1 = MFMA16(av1, zc2, zero4);
    f32x4 p0h0 = MFMA16(av0, zc1, zero4);
    f32x4 p1h0 = MFMA16(av0, zc2, zero4);
    f32x4 p2h0 = MFMA16(av0, zc3, zero4);
    if (kt == q0) {   // diagonal block: add the pA term (zc was from pZb)
      const int mb = kt - q0 + (S - 32);
      bf16x8 y0 = *(const bf16x8*)(pAb + (size_t)(mb + lm) * Dh + lg * 8);
      bf16x8 y1 = *(const bf16x8*)(pAb + (size_t)(mb + 16 + lm) * Dh + lg * 8);
      bf16x8 y2 = *(const bf16x8*)(pAb + (size_t)(mb + 32 + lm) * Dh + lg * 8);
      bf16x8 y3 = *(const bf16x8*)(pAb + (size_t)(mb + 48 + lm) * Dh + lg * 8);
      p0h1 = MFMA16(avA1, y0, p0h1);
      p1h1 = MFMA16(avA1, y1, p1h1);
      p2h1 = MFMA16(avA1, y2, p2h1);
      p0h0 = MFMA16(avA0, y1, p0h0);
      p1h0 = MFMA16(avA0, y2, p1h0);
      p2h0 = MFMA16(avA0, y3, p2h0);
    }

    // ---- diagonal gather (register shuffles) + exp + packed P store
#pragma unroll
    for (int r = 0; r < 4; ++r) {
      const float a0 = __shfl(p0h0[r], slr[r], 64);
      const float a1 = __shfl(p1h0[r], slr[r], 64);
      const float a2 = __shfl(p2h0[r], slr[r], 64);
      const float b0 = __shfl(p0h1[r], slr[r], 64);
      const float b1 = __shfl(p1h1[r], slr[r], 64);
      const float b2 = __shfl(p2h1[r], slr[r], 64);
      const float s00 = c00[r] + (prd[r] ? a0 : a1);
      const float s10 = c10[r] + (prd[r] ? a1 : a2);
      const float s01 = c01[r] + (prd[r] ? b0 : b1);
      const float s11 = c11[r] + (prd[r] ? b1 : b2);
      bf16x2 pp0; pp0[0] = (__bf16)__expf(s00); pp0[1] = (__bf16)__expf(s10);
      bf16x2 pp1; pp1[0] = (__bf16)__expf(s01); pp1[1] = (__bf16)__expf(s11);
      *(bf16x2*)(at + (lg * 4 + r) * 40 + 2 * lm) = pp0;
      *(bf16x2*)(at + (16 + lg * 4 + r) * 40 + 2 * lm) = pp1;
    }

    // ---- attn @ V + row-sum via ones-MFMA (reuses P fragments)
    bf16x8 af0 = *(const bf16x8*)(at + lm * 40 + lg * 8);
    bf16x8 af1 = *(const bf16x8*)(at + (lm + 16) * 40 + lg * 8);
    bf16x8 vf0 = *(const bf16x8*)(Vs + lm * 32 + cc);
    bf16x8 vf1 = *(const bf16x8*)(Vs + (lm + 16) * 32 + cc);
    ca0 = MFMA16(af0, vf0, ca0);
    cb0 = MFMA16(af0, vf1, cb0);
    ca1 = MFMA16(af1, vf0, ca1);
    cb1 = MFMA16(af1, vf1, cb1);
    ls0 = MFMA16(af0, ones8, ls0);
    ls1 = MFMA16(af1, ones8, ls1);

    // ---- rotate Z registers (the copies force the vmcnt wait here, after a
    // full body of slack), then stage tile t+2 and cross the barrier with the
    // newest stage still in flight (vmcnt(1), never 0).
    zc0 = zn0; zc1 = zn1; zc2 = zn2; zc3 = zn3;
    useBc = useBn;
    __builtin_amdgcn_sched_barrier(0);
    stage((kt + 64 < S) ? kt + 64 : kt, (tb + 2) & 3);
    asm volatile("s_waitcnt vmcnt(1)" ::: "memory");
    __builtin_amdgcn_s_barrier();
  }

  // ---- normalize + store ctx (ls[r] = row sum, identical across lm lanes)
#pragma unroll
  for (int r = 0; r < 4; ++r) {
    const int s0 = q0 + lg * 4 + r;
    const float invA = 1.f / ls0[r];
    const float invB = 1.f / ls1[r];
    __bf16* cp0 = ctx + ((size_t)b * S + s0) * DIM + h * Dh;
    __bf16* cp1 = ctx + ((size_t)b * S + s0 + 16) * DIM + h * Dh;
    cp0[lm]      = (__bf16)(ca0[r] * invA);
    cp0[16 + lm] = (__bf16)(cb0[r] * invA);
    cp1[lm]      = (__bf16)(ca1[r] * invB);
    cp1[16 + lm] = (__bf16)(cb1[r] * invB);
  }
}

// ---------------------------------------------------------------------------
extern "C" void kernel_launch(void* const* d_in, const int* in_sizes, int n_in,
                              void* d_out, int out_size, void* d_ws, size_t ws_size,
                              hipStream_t stream) {
  const float* query = (const float*)d_in[0];
  const float* key   = (const float*)d_in[1];
  const float* value = (const float*)d_in[2];
  const float* pos   = (const float*)d_in[3];
  const float* Wq = (const float*)d_in[4];
  const float* bq = (const float*)d_in[5];
  const float* Wk = (const float*)d_in[6];
  const float* bk = (const float*)d_in[7];
  const float* Wv = (const float*)d_in[8];
  const float* bv = (const float*)d_in[9];
  const float* Wp = (const float*)d_in[10];
  const float* ub = (const float*)d_in[11];
  const float* vb = (const float*)d_in[12];
  const float* Wo = (const float*)d_in[13];
  const float* bo = (const float*)d_in[14];
  float* out = (float*)d_out;

  char* ws = (char*)d_ws;
  const size_t MB = 1ull << 20;
  // Layout:
  //   [ 0,16) MB : xb (4x bf16 activations)
  //   [16,18.5)  : wb (5x bf16 weights)
  //   [19,23)    : qu   [23,27): qv   [27,31): kk   [31,35): vt
  //   [35,47.7)  : phZ [B*H, 3S+16, 32]
  //   [48,52)    : ctx bf16
  __bf16* xb  = (__bf16*)(ws + 0 * MB);
  __bf16* wb  = (__bf16*)(ws + 16 * MB);
  __bf16* qu  = (__bf16*)(ws + 19 * MB);
  __bf16* qv  = (__bf16*)(ws + 23 * MB);
  __bf16* kk  = (__bf16*)(ws + 27 * MB);
  __bf16* vt  = (__bf16*)(ws + 31 * MB);
  __bf16* phZ = (__bf16*)(ws + 35 * MB);
  __bf16* ctx = (__bf16*)(ws + 48 * MB);

  conv_kernel<<<dim3(1024, 9), dim3(256), 0, stream>>>(
      query, key, value, pos, Wq, Wk, Wv, Wp, Wo, xb, wb);

  hipMemsetAsync(phZ, 0, (size_t)64 * ZROWS * Dh * sizeof(__bf16), stream);

  gemm_kernel<<<dim3(512), dim3(256), 0, stream>>>(
      xb, wb, ctx, bq, bk, bv, bo, ub, vb,
      qu, qv, kk, vt, phZ, out, 0);

  attn_kernel<<<dim3(512), dim3(256), 0, stream>>>(
      qu, qv, kk, vt, phZ, ctx);

  gemm_kernel<<<dim3(128), dim3(256), 0, stream>>>(
      xb, wb, ctx, bq, bk, bv, bo, ub, vb,
      qu, qv, kk, vt, phZ, out, 1);
}

// Round 12
// 98.374 us; speedup vs baseline: 1.0560x; 1.0560x over previous
//
#include <hip/hip_runtime.h>
#include <hip/hip_bf16.h>
#include <math.h>

// Transformer-XL relative multi-head attention, bf16 MFMA implementation.
// B=4, S=1024, H=16, Dh=32, DIM=512.
//
// relative_shift identity: shifted[q,k] = qv[q]·pA[m] + qv[q+1]·pB[m],
// m = k - q + S - 1;  pA[m]=Z[S+1+m], pB[m]=Z[m] with a single zero-padded
// tensor Z (rows [S+1, 2S+1) = p, all else 0).
//
// Round 12: (1) attn at 16 q-rows/wave (grid 1024, 4 blocks/CU -> 16
// waves/CU, 2x R11) keeping the R11 pipeline; Z windows register-double-
// buffered (named zA/zB sets, 2-half unrolled loop — no rotate-drain);
// counted vmcnt(4) before each barrier (waits exactly the stage the next
// half needs; 3 Z + newest stage stay in flight). (2) gemm reverted to
// R10's BK=64 / 2-barrier version (R11's BK=32 cost ~5us).

typedef float f32x4 __attribute__((ext_vector_type(4)));
typedef __bf16 bf16x8 __attribute__((ext_vector_type(8)));
typedef __bf16 bf16x2 __attribute__((ext_vector_type(2)));

#define MFMA16(a, b, c) __builtin_amdgcn_mfma_f32_16x16x32_bf16((a), (b), (c), 0, 0, 0)

constexpr int Bb  = 4;
constexpr int S   = 1024;
constexpr int H   = 16;
constexpr int Dh  = 32;
constexpr int DIM = 512;
constexpr float SCALE = 0.17677669529663687f;  // 1/sqrt(32)
constexpr int ZROWS = 3 * S + 16;              // phZ rows per (b,h)

constexpr size_t XN = (size_t)Bb * S * DIM;   // elems per activation tensor
constexpr size_t WN = (size_t)DIM * DIM;      // elems per weight matrix

__device__ inline bf16x8 cvt8(const float* __restrict__ p) {
  f32x4 a = *(const f32x4*)p;
  f32x4 b = *(const f32x4*)(p + 4);
  bf16x8 r;
  r[0] = (__bf16)a[0]; r[1] = (__bf16)a[1]; r[2] = (__bf16)a[2]; r[3] = (__bf16)a[3];
  r[4] = (__bf16)b[0]; r[5] = (__bf16)b[1]; r[6] = (__bf16)b[2]; r[7] = (__bf16)b[3];
  return r;
}

__device__ inline void gload_lds16(const __bf16* g, __bf16* l) {
  __builtin_amdgcn_global_load_lds(
      (const __attribute__((address_space(1))) unsigned int*)g,
      (__attribute__((address_space(3))) unsigned int*)l, 16, 0, 0);
}

// ---------------------------------------------------------------------------
// Kernel 0: f32 -> bf16 conversion of activations (y=0..3) and weights (y=4..8).
// ---------------------------------------------------------------------------
__global__ __launch_bounds__(256) void conv_kernel(
    const float* __restrict__ q, const float* __restrict__ k,
    const float* __restrict__ v, const float* __restrict__ p,
    const float* __restrict__ wq, const float* __restrict__ wk,
    const float* __restrict__ wv, const float* __restrict__ wp,
    const float* __restrict__ wo,
    __bf16* __restrict__ xb, __bf16* __restrict__ wb)
{
  const int y = blockIdx.y;
  const float* src;
  size_t n;
  __bf16* dst;
  if (y < 4) {
    src = (y == 0) ? q : (y == 1) ? k : (y == 2) ? v : p;
    n = XN;
    dst = xb + (size_t)y * XN;
  } else {
    const int w = y - 4;
    src = (w == 0) ? wq : (w == 1) ? wk : (w == 2) ? wv : (w == 3) ? wp : wo;
    n = WN;
    dst = wb + (size_t)w * WN;
  }
  const size_t i = ((size_t)blockIdx.x * 256 + threadIdx.x) * 8;
  if (i >= n) return;
  *(bf16x8*)(dst + i) = cvt8(src + i);
}

// ---------------------------------------------------------------------------
// Kernel 1: tiled bf16 GEMM  C[M, N=512] = A @ B^T, K=512.  (R10 version)
// 128x128 block tile, BK=64, 4 waves. global_load_lds(16B), XOR-swizzled
// source + read (linear LDS dest). XCD co-location of col-blocks.
// mode 0: z=0..3 projections; mode 1: z=4 outproj (f32 + bo).
// ---------------------------------------------------------------------------
__global__ __launch_bounds__(256) void gemm_kernel(
    const __bf16* __restrict__ xb, const __bf16* __restrict__ wb,
    const __bf16* __restrict__ ctxp,
    const float* __restrict__ bq, const float* __restrict__ bk,
    const float* __restrict__ bv, const float* __restrict__ bo,
    const float* __restrict__ ub, const float* __restrict__ vb,
    __bf16* __restrict__ qu, __bf16* __restrict__ qv,
    __bf16* __restrict__ kk, __bf16* __restrict__ vt,
    __bf16* __restrict__ phZ,
    float* __restrict__ outp, int mode)
{
  __shared__ __align__(16) __bf16 As[128 * 64];
  __shared__ __align__(16) __bf16 Bs[128 * 64];

  const int bid = blockIdx.x;
  const int u = bid >> 3;
  const int by = u & 3;
  const int idx = (bid & 7) + 8 * (u >> 2);
  int bx, z;
  if (mode == 0) { bx = idx & 31; z = idx >> 5; }
  else           { bx = idx;      z = 4; }

  const __bf16* Ag = (z < 4) ? (xb + (size_t)z * XN) : ctxp;
  const __bf16* Bg = wb + (size_t)z * WN;

  const int tid = threadIdx.x;
  const int wid = tid >> 6;
  const int ln = tid & 63;
  const int lm = ln & 15, lg = ln >> 4;
  const int wr = wid >> 1, wc = wid & 1;
  const int brow = bx * 128;
  const int bcol = by * 128;

  const int srow = ln >> 3;
  const int sc   = ln & 7;

  f32x4 acc[4][4] = {};

  for (int kt = 0; kt < DIM / 64; ++kt) {
    const int k0 = kt * 64;
#pragma unroll
    for (int i = 0; i < 4; ++i) {
      const int rb = wid * 32 + i * 8;
      const int r = rb + srow;
      const int cg = sc ^ (r & 7);
      gload_lds16(Ag + (size_t)(brow + r) * DIM + k0 + cg * 8, &As[rb * 64]);
      gload_lds16(Bg + (size_t)(bcol + r) * DIM + k0 + cg * 8, &Bs[rb * 64]);
    }
    __syncthreads();

#pragma unroll
    for (int ks = 0; ks < 2; ++ks) {
      bf16x8 a[4], b[4];
#pragma unroll
      for (int m = 0; m < 4; ++m) {
        const int row = wr * 64 + m * 16 + lm;
        const int cc = (ks * 4 + lg) ^ (row & 7);
        a[m] = *(const bf16x8*)&As[row * 64 + cc * 8];
      }
#pragma unroll
      for (int n = 0; n < 4; ++n) {
        const int row = wc * 64 + n * 16 + lm;
        const int cc = (ks * 4 + lg) ^ (row & 7);
        b[n] = *(const bf16x8*)&Bs[row * 64 + cc * 8];
      }
#pragma unroll
      for (int m = 0; m < 4; ++m)
#pragma unroll
        for (int n = 0; n < 4; ++n)
          acc[m][n] = MFMA16(a[m], b[n], acc[m][n]);
    }
    __syncthreads();
  }

  // ---- epilogue
#pragma unroll
  for (int n = 0; n < 4; ++n) {
    const int o = bcol + wc * 64 + n * 16 + lm;
    float bias = 0.f, ubv = 0.f, vbv = 0.f;
    if (z == 0) { bias = bq[o]; ubv = ub[o]; vbv = vb[o]; }
    else if (z == 1) bias = bk[o];
    else if (z == 2) bias = bv[o];
    else if (z == 4) bias = bo[o];
    const int h = o >> 5, d = o & 31;
#pragma unroll
    for (int m = 0; m < 4; ++m) {
#pragma unroll
      for (int r = 0; r < 4; ++r) {
        const int M = brow + wr * 64 + m * 16 + lg * 4 + r;
        const float val = acc[m][n][r];
        if (z == 4) {
          outp[(size_t)M * DIM + o] = val + bias;
          continue;
        }
        const int b = M >> 10, s = M & (S - 1);
        const int bh = b * H + h;
        if (z == 0) {
          // 1/sqrt(Dh) folded in here (scores use pre-scaled q).
          const size_t idx2 = ((size_t)bh * S + s) * Dh + d;
          qu[idx2] = (__bf16)((val + bias + ubv) * SCALE);
          qv[idx2] = (__bf16)((val + bias + vbv) * SCALE);
        } else if (z == 1) {
          kk[((size_t)bh * S + s) * Dh + d] = (__bf16)(val + bias);
        } else if (z == 2) {
          // V^T with k-interleaved columns within each 32-block:
          // pos(t) = 2t (t<16) else 2t-31 -> matches attn's packed P stores.
          const int t = s & 31;
          const int sp = (s & ~31) | ((t < 16) ? (t << 1) : ((t << 1) - 31));
          vt[((size_t)bh * Dh + d) * S + sp] = (__bf16)(val + bias);
        } else {
          // phZ rows [S+1, 2S+1) = p; everything else pre-zeroed by memset.
          phZ[((size_t)bh * ZROWS + (S + 1 + s)) * Dh + d] = (__bf16)val;
        }
      }
    }
  }
}

// ---------------------------------------------------------------------------
// Kernel 2: fused attention. 256-thread blocks, 4 waves x 16 q-rows (grid
// 1024 -> 4 blocks/CU, 16 waves/CU). K/V staged 2 tiles ahead in 4 LDS
// buffers (XOR-swizzled); Z windows register-double-buffered across a
// 2-half unrolled loop; counted vmcnt(4) barriers; ones-MFMA row sums;
// max-free softmax; pos diagonal gather via __shfl.
// ---------------------------------------------------------------------------
__global__ __launch_bounds__(256, 4) void attn_kernel(
    const __bf16* __restrict__ qu, const __bf16* __restrict__ qv,
    const __bf16* __restrict__ kk, const __bf16* __restrict__ vt,
    const __bf16* __restrict__ phZ,
    __bf16* __restrict__ ctx)
{
  __shared__ __align__(16) __bf16 kv_lds[4][2][1024];  // [buf][K|V][32x32]
  __shared__ __align__(16) __bf16 at_all[4][16 * 40];

  const int tid = threadIdx.x;
  const int wid = tid >> 6;
  const int l = tid & 63;
  const int lm = l & 15, lg = l >> 4;

  const int bid = blockIdx.x;               // [0, 1024)
  const int bh = (bid & 7) + 8 * ((bid >> 3) & 7);  // bh resident on XCD bid&7
  const int q0 = (bid >> 6) * 64 + wid * 16;
  const int h = bh & (H - 1), b = bh >> 4;

  const __bf16* qub = qu + (size_t)bh * S * Dh;
  const __bf16* qvb = qv + (size_t)bh * S * Dh;
  const __bf16* kb  = kk + (size_t)bh * S * Dh;
  const __bf16* vtb = vt + (size_t)bh * Dh * S;
  const __bf16* pZb = phZ + (size_t)bh * ZROWS * Dh;
  const __bf16* pAb = pZb + (size_t)(S + 1) * Dh;   // pA[m] = Z[S+1+m]

  const bf16x8 au  = *(const bf16x8*)(qub + (size_t)(q0 + lm) * Dh + lg * 8);
  const bf16x8 avA = *(const bf16x8*)(qvb + (size_t)(q0 + lm) * Dh + lg * 8);
  // row q+1 for the pB term; one-past reads hit allocated memory and are
  // multiplied by pB rows that are exactly zero wherever consumed.
  const bf16x8 avB = *(const bf16x8*)(qvb + (size_t)(q0 + 1 + lm) * Dh + lg * 8);

  int  slr[4];
  bool prd[4];
#pragma unroll
  for (int r = 0; r < 4; ++r) {
    const int qr = lg * 4 + r;
    slr[r] = (l & 48) | ((lm - qr + 15) & 15);
    prd[r] = (lm <= qr);
  }

  bf16x8 ones8;
#pragma unroll
  for (int i = 0; i < 8; ++i) ones8[i] = (__bf16)1.0f;

  f32x4 cta = {0.f,0.f,0.f,0.f}, ctb = {0.f,0.f,0.f,0.f};
  f32x4 ls  = {0.f,0.f,0.f,0.f};
  const f32x4 zero4 = {0.f,0.f,0.f,0.f};

  const int srow = l >> 2;
  const int scg  = ((l & 3) ^ (srow & 3)) * 8;
  auto stage = [&](int kt, int buf) {
    const __bf16* src;
    if (wid == 0)      src = kb  + (size_t)(kt + srow) * Dh + scg;
    else if (wid == 1) src = kb  + (size_t)(kt + 16 + srow) * Dh + scg;
    else if (wid == 2) src = vtb + (size_t)srow * S + kt + scg;
    else               src = vtb + (size_t)(16 + srow) * S + kt + scg;
    gload_lds16(src, &kv_lds[buf][wid >> 1][(wid & 1) * 512]);
  };

  const int cc = (lg ^ (lm & 3)) * 8;
  __bf16* at = at_all[wid];

  // Z-window prefetch into a named register set (3 tiles of 16 rows).
  auto zwin = [&](int kt, bf16x8& z0, bf16x8& z1, bf16x8& z2, bool& uB) {
    const int ktc = (kt < S) ? kt : (S - 32);
    uB = (ktc > q0 - 31);
    const int mb = ktc - q0 + (S - 16);
    const __bf16* zb = uB ? pZb : pAb;
    z0 = *(const bf16x8*)(zb + (size_t)(mb + lm) * Dh + lg * 8);
    z1 = *(const bf16x8*)(zb + (size_t)(mb + 16 + lm) * Dh + lg * 8);
    z2 = *(const bf16x8*)(zb + (size_t)(mb + 32 + lm) * Dh + lg * 8);
  };

  // One 32-k tile using a resident Z register set.
  auto half = [&](int kt, int tb, bf16x8 z0, bf16x8 z1, bf16x8 z2, bool uB) {
    const __bf16* Ks = kv_lds[tb][0];
    const __bf16* Vs = kv_lds[tb][1];
    bf16x8 kf0 = *(const bf16x8*)(Ks + lm * 32 + cc);
    bf16x8 kf1 = *(const bf16x8*)(Ks + (lm + 16) * 32 + cc);
    f32x4 c0 = MFMA16(au, kf0, zero4);
    f32x4 c1 = MFMA16(au, kf1, zero4);

    const bf16x8 av = uB ? avB : avA;
    f32x4 pt0 = MFMA16(av, z0, zero4);
    f32x4 pt1 = MFMA16(av, z1, zero4);
    f32x4 pt2 = MFMA16(av, z2, zero4);
    if (uB && (kt < q0 + 16)) {   // diagonal band (once per wave): add pA term
      const int mb = kt - q0 + (S - 16);
      bf16x8 y0 = *(const bf16x8*)(pAb + (size_t)(mb + lm) * Dh + lg * 8);
      bf16x8 y1 = *(const bf16x8*)(pAb + (size_t)(mb + 16 + lm) * Dh + lg * 8);
      bf16x8 y2 = *(const bf16x8*)(pAb + (size_t)(mb + 32 + lm) * Dh + lg * 8);
      pt0 = MFMA16(avA, y0, pt0);
      pt1 = MFMA16(avA, y1, pt1);
      pt2 = MFMA16(avA, y2, pt2);
    }

#pragma unroll
    for (int r = 0; r < 4; ++r) {
      const float v0 = __shfl(pt0[r], slr[r], 64);
      const float v1 = __shfl(pt1[r], slr[r], 64);
      const float v2 = __shfl(pt2[r], slr[r], 64);
      const float s0 = c0[r] + (prd[r] ? v0 : v1);
      const float s1 = c1[r] + (prd[r] ? v1 : v2);
      bf16x2 pp;
      pp[0] = (__bf16)__expf(s0);            // k-col kt+lm     -> pos 2*lm
      pp[1] = (__bf16)__expf(s1);            // k-col kt+16+lm  -> pos 2*lm+1
      *(bf16x2*)(at + (lg * 4 + r) * 40 + 2 * lm) = pp;
    }

    bf16x8 af  = *(const bf16x8*)(at + lm * 40 + lg * 8);
    bf16x8 vf0 = *(const bf16x8*)(Vs + lm * 32 + cc);
    bf16x8 vf1 = *(const bf16x8*)(Vs + (lm + 16) * 32 + cc);
    cta = MFMA16(af, vf0, cta);
    ctb = MFMA16(af, vf1, ctb);
    ls  = MFMA16(af, ones8, ls);
  };

  // ---- prologue: Z(0) + stage tiles 0,1; wait all but newest stage.
  bf16x8 zA0, zA1, zA2, zB0, zB1, zB2;
  bool uA, uB;
  zwin(0, zA0, zA1, zA2, uA);
  stage(0, 0);
  stage(32, 1);
  asm volatile("s_waitcnt vmcnt(1)" ::: "memory");
  __builtin_amdgcn_s_barrier();

  for (int kt = 0; kt < S; kt += 64) {
    const int t = kt >> 5;
    // half A: tile kt (buf t&3), consume zA, prefetch zB for kt+32
    zwin(kt + 32, zB0, zB1, zB2, uB);
    half(kt, t & 3, zA0, zA1, zA2, uA);
    stage((kt + 64 < S) ? kt + 64 : kt, (t + 2) & 3);
    asm volatile("s_waitcnt vmcnt(4)" ::: "memory");
    __builtin_amdgcn_s_barrier();

    // half B: tile kt+32 (buf (t+1)&3), consume zB, prefetch zA for kt+64
    zwin(kt + 64, zA0, zA1, zA2, uA);
    half(kt + 32, (t + 1) & 3, zB0, zB1, zB2, uB);
    stage((kt + 96 < S) ? kt + 96 : kt, (t + 3) & 3);
    asm volatile("s_waitcnt vmcnt(4)" ::: "memory");
    __builtin_amdgcn_s_barrier();
  }

  // ---- normalize + store ctx (ls[r] = row sum, identical across lm lanes)
#pragma unroll
  for (int r = 0; r < 4; ++r) {
    const int s0 = q0 + lg * 4 + r;
    const float inv = 1.f / ls[r];
    __bf16* cp = ctx + ((size_t)b * S + s0) * DIM + h * Dh;
    cp[lm]      = (__bf16)(cta[r] * inv);
    cp[16 + lm] = (__bf16)(ctb[r] * inv);
  }
}

// ---------------------------------------------------------------------------
extern "C" void kernel_launch(void* const* d_in, const int* in_sizes, int n_in,
                              void* d_out, int out_size, void* d_ws, size_t ws_size,
                              hipStream_t stream) {
  const float* query = (const float*)d_in[0];
  const float* key   = (const float*)d_in[1];
  const float* value = (const float*)d_in[2];
  const float* pos   = (const float*)d_in[3];
  const float* Wq = (const float*)d_in[4];
  const float* bq = (const float*)d_in[5];
  const float* Wk = (const float*)d_in[6];
  const float* bk = (const float*)d_in[7];
  const float* Wv = (const float*)d_in[8];
  const float* bv = (const float*)d_in[9];
  const float* Wp = (const float*)d_in[10];
  const float* ub = (const float*)d_in[11];
  const float* vb = (const float*)d_in[12];
  const float* Wo = (const float*)d_in[13];
  const float* bo = (const float*)d_in[14];
  float* out = (float*)d_out;

  char* ws = (char*)d_ws;
  const size_t MB = 1ull << 20;
  // Layout:
  //   [ 0,16) MB : xb (4x bf16 activations)
  //   [16,18.5)  : wb (5x bf16 weights)
  //   [19,23)    : qu   [23,27): qv   [27,31): kk   [31,35): vt
  //   [35,47.7)  : phZ [B*H, 3S+16, 32]
  //   [48,52)    : ctx bf16
  __bf16* xb  = (__bf16*)(ws + 0 * MB);
  __bf16* wb  = (__bf16*)(ws + 16 * MB);
  __bf16* qu  = (__bf16*)(ws + 19 * MB);
  __bf16* qv  = (__bf16*)(ws + 23 * MB);
  __bf16* kk  = (__bf16*)(ws + 27 * MB);
  __bf16* vt  = (__bf16*)(ws + 31 * MB);
  __bf16* phZ = (__bf16*)(ws + 35 * MB);
  __bf16* ctx = (__bf16*)(ws + 48 * MB);

  conv_kernel<<<dim3(1024, 9), dim3(256), 0, stream>>>(
      query, key, value, pos, Wq, Wk, Wv, Wp, Wo, xb, wb);

  hipMemsetAsync(phZ, 0, (size_t)64 * ZROWS * Dh * sizeof(__bf16), stream);

  gemm_kernel<<<dim3(512), dim3(256), 0, stream>>>(
      xb, wb, ctx, bq, bk, bv, bo, ub, vb,
      qu, qv, kk, vt, phZ, out, 0);

  attn_kernel<<<dim3(1024), dim3(256), 0, stream>>>(
      qu, qv, kk, vt, phZ, ctx);

  gemm_kernel<<<dim3(128), dim3(256), 0, stream>>>(
      xb, wb, ctx, bq, bk, bv, bo, ub, vb,
      qu, qv, kk, vt, phZ, out, 1);
}

// Round 13
// 95.622 us; speedup vs baseline: 1.0864x; 1.0288x over previous
//
#include <hip/hip_runtime.h>
#include <hip/hip_bf16.h>
#include <math.h>

// Transformer-XL relative multi-head attention, bf16 MFMA implementation.
// B=4, S=1024, H=16, Dh=32, DIM=512.
//
// relative_shift identity: shifted[q,k] = qv[q]·pA[m] + qv[q+1]·pB[m],
// m = k - q + S - 1;  pA[m]=Z[S+1+m], pB[m]=Z[m] with a single zero-padded
// tensor Z (rows [S+1, 2S+1) = p, all else 0).
//
// Round 13: attn sync-slop reduction. ONE barrier per 64-k (was 2): stages
// for the next 64-k issue at body start (full-body slack), zB loads before
// halfA, zA' loads between halves and stay in flight ACROSS the barrier
// (vmcnt(3), never 0). Split P buffers per half (no WAR). setprio(1)
// around MFMA clusters (T5). exp2 fold: SCALE*log2(e) baked into the q
// projections -> raw v_exp_f32. conv kernel absorbs phZ zeroing (one
// fewer launch). gemm unchanged (R10 version).

typedef float f32x4 __attribute__((ext_vector_type(4)));
typedef __bf16 bf16x8 __attribute__((ext_vector_type(8)));
typedef __bf16 bf16x2 __attribute__((ext_vector_type(2)));

#define MFMA16(a, b, c) __builtin_amdgcn_mfma_f32_16x16x32_bf16((a), (b), (c), 0, 0, 0)

constexpr int Bb  = 4;
constexpr int S   = 1024;
constexpr int H   = 16;
constexpr int Dh  = 32;
constexpr int DIM = 512;
// 1/sqrt(32) * log2(e): scores come out pre-scaled for v_exp_f32 (=2^x).
constexpr float SCALEL2E = 0.25501818637084186f;
constexpr int ZROWS = 3 * S + 16;              // phZ rows per (b,h)
constexpr size_t ZN = (size_t)64 * ZROWS * Dh; // phZ total elements

constexpr size_t XN = (size_t)Bb * S * DIM;   // elems per activation tensor
constexpr size_t WN = (size_t)DIM * DIM;      // elems per weight matrix

__device__ inline bf16x8 cvt8(const float* __restrict__ p) {
  f32x4 a = *(const f32x4*)p;
  f32x4 b = *(const f32x4*)(p + 4);
  bf16x8 r;
  r[0] = (__bf16)a[0]; r[1] = (__bf16)a[1]; r[2] = (__bf16)a[2]; r[3] = (__bf16)a[3];
  r[4] = (__bf16)b[0]; r[5] = (__bf16)b[1]; r[6] = (__bf16)b[2]; r[7] = (__bf16)b[3];
  return r;
}

__device__ inline float fexp2(float x) {
  float r;
  asm("v_exp_f32 %0, %1" : "=v"(r) : "v"(x));
  return r;
}

__device__ inline void gload_lds16(const __bf16* g, __bf16* l) {
  __builtin_amdgcn_global_load_lds(
      (const __attribute__((address_space(1))) unsigned int*)g,
      (__attribute__((address_space(3))) unsigned int*)l, 16, 0, 0);
}

// ---------------------------------------------------------------------------
// Kernel 0: f32 -> bf16 conversion (y=0..8) + phZ zero-fill (y=9..12).
// ---------------------------------------------------------------------------
__global__ __launch_bounds__(256) void conv_kernel(
    const float* __restrict__ q, const float* __restrict__ k,
    const float* __restrict__ v, const float* __restrict__ p,
    const float* __restrict__ wq, const float* __restrict__ wk,
    const float* __restrict__ wv, const float* __restrict__ wp,
    const float* __restrict__ wo,
    __bf16* __restrict__ xb, __bf16* __restrict__ wb,
    __bf16* __restrict__ phZ)
{
  const int y = blockIdx.y;
  if (y >= 9) {
    const size_t i = (((size_t)(y - 9) * 1024 + blockIdx.x) * 256 + threadIdx.x) * 8;
    if (i < ZN) {
      bf16x8 zz = {};
      *(bf16x8*)(phZ + i) = zz;
    }
    return;
  }
  const float* src;
  size_t n;
  __bf16* dst;
  if (y < 4) {
    src = (y == 0) ? q : (y == 1) ? k : (y == 2) ? v : p;
    n = XN;
    dst = xb + (size_t)y * XN;
  } else {
    const int w = y - 4;
    src = (w == 0) ? wq : (w == 1) ? wk : (w == 2) ? wv : (w == 3) ? wp : wo;
    n = WN;
    dst = wb + (size_t)w * WN;
  }
  const size_t i = ((size_t)blockIdx.x * 256 + threadIdx.x) * 8;
  if (i >= n) return;
  *(bf16x8*)(dst + i) = cvt8(src + i);
}

// ---------------------------------------------------------------------------
// Kernel 1: tiled bf16 GEMM  C[M, N=512] = A @ B^T, K=512.  (R10 version)
// 128x128 block tile, BK=64, 4 waves. global_load_lds(16B), XOR-swizzled
// source + read (linear LDS dest). XCD co-location of col-blocks.
// mode 0: z=0..3 projections; mode 1: z=4 outproj (f32 + bo).
// ---------------------------------------------------------------------------
__global__ __launch_bounds__(256) void gemm_kernel(
    const __bf16* __restrict__ xb, const __bf16* __restrict__ wb,
    const __bf16* __restrict__ ctxp,
    const float* __restrict__ bq, const float* __restrict__ bk,
    const float* __restrict__ bv, const float* __restrict__ bo,
    const float* __restrict__ ub, const float* __restrict__ vb,
    __bf16* __restrict__ qu, __bf16* __restrict__ qv,
    __bf16* __restrict__ kk, __bf16* __restrict__ vt,
    __bf16* __restrict__ phZ,
    float* __restrict__ outp, int mode)
{
  __shared__ __align__(16) __bf16 As[128 * 64];
  __shared__ __align__(16) __bf16 Bs[128 * 64];

  const int bid = blockIdx.x;
  const int u = bid >> 3;
  const int by = u & 3;
  const int idx = (bid & 7) + 8 * (u >> 2);
  int bx, z;
  if (mode == 0) { bx = idx & 31; z = idx >> 5; }
  else           { bx = idx;      z = 4; }

  const __bf16* Ag = (z < 4) ? (xb + (size_t)z * XN) : ctxp;
  const __bf16* Bg = wb + (size_t)z * WN;

  const int tid = threadIdx.x;
  const int wid = tid >> 6;
  const int ln = tid & 63;
  const int lm = ln & 15, lg = ln >> 4;
  const int wr = wid >> 1, wc = wid & 1;
  const int brow = bx * 128;
  const int bcol = by * 128;

  const int srow = ln >> 3;
  const int sc   = ln & 7;

  f32x4 acc[4][4] = {};

  for (int kt = 0; kt < DIM / 64; ++kt) {
    const int k0 = kt * 64;
#pragma unroll
    for (int i = 0; i < 4; ++i) {
      const int rb = wid * 32 + i * 8;
      const int r = rb + srow;
      const int cg = sc ^ (r & 7);
      gload_lds16(Ag + (size_t)(brow + r) * DIM + k0 + cg * 8, &As[rb * 64]);
      gload_lds16(Bg + (size_t)(bcol + r) * DIM + k0 + cg * 8, &Bs[rb * 64]);
    }
    __syncthreads();

#pragma unroll
    for (int ks = 0; ks < 2; ++ks) {
      bf16x8 a[4], b[4];
#pragma unroll
      for (int m = 0; m < 4; ++m) {
        const int row = wr * 64 + m * 16 + lm;
        const int cc = (ks * 4 + lg) ^ (row & 7);
        a[m] = *(const bf16x8*)&As[row * 64 + cc * 8];
      }
#pragma unroll
      for (int n = 0; n < 4; ++n) {
        const int row = wc * 64 + n * 16 + lm;
        const int cc = (ks * 4 + lg) ^ (row & 7);
        b[n] = *(const bf16x8*)&Bs[row * 64 + cc * 8];
      }
#pragma unroll
      for (int m = 0; m < 4; ++m)
#pragma unroll
        for (int n = 0; n < 4; ++n)
          acc[m][n] = MFMA16(a[m], b[n], acc[m][n]);
    }
    __syncthreads();
  }

  // ---- epilogue
#pragma unroll
  for (int n = 0; n < 4; ++n) {
    const int o = bcol + wc * 64 + n * 16 + lm;
    float bias = 0.f, ubv = 0.f, vbv = 0.f;
    if (z == 0) { bias = bq[o]; ubv = ub[o]; vbv = vb[o]; }
    else if (z == 1) bias = bk[o];
    else if (z == 2) bias = bv[o];
    else if (z == 4) bias = bo[o];
    const int h = o >> 5, d = o & 31;
#pragma unroll
    for (int m = 0; m < 4; ++m) {
#pragma unroll
      for (int r = 0; r < 4; ++r) {
        const int M = brow + wr * 64 + m * 16 + lg * 4 + r;
        const float val = acc[m][n][r];
        if (z == 4) {
          outp[(size_t)M * DIM + o] = val + bias;
          continue;
        }
        const int b = M >> 10, s = M & (S - 1);
        const int bh = b * H + h;
        if (z == 0) {
          // 1/sqrt(Dh)*log2(e) folded in (scores feed v_exp_f32 directly).
          const size_t idx2 = ((size_t)bh * S + s) * Dh + d;
          qu[idx2] = (__bf16)((val + bias + ubv) * SCALEL2E);
          qv[idx2] = (__bf16)((val + bias + vbv) * SCALEL2E);
        } else if (z == 1) {
          kk[((size_t)bh * S + s) * Dh + d] = (__bf16)(val + bias);
        } else if (z == 2) {
          // V^T with k-interleaved columns within each 32-block:
          // pos(t) = 2t (t<16) else 2t-31 -> matches attn's packed P stores.
          const int t = s & 31;
          const int sp = (s & ~31) | ((t < 16) ? (t << 1) : ((t << 1) - 31));
          vt[((size_t)bh * Dh + d) * S + sp] = (__bf16)(val + bias);
        } else {
          // phZ rows [S+1, 2S+1) = p; everything else pre-zeroed by conv.
          phZ[((size_t)bh * ZROWS + (S + 1 + s)) * Dh + d] = (__bf16)val;
        }
      }
    }
  }
}

// ---------------------------------------------------------------------------
// Kernel 2: fused attention. 256-thread blocks, 4 waves x 16 q-rows (grid
// 1024, 4 blocks/CU). K/V staged 2 64-k groups ahead in 4 LDS buffers
// (XOR-swizzled); Z windows register-double-buffered; ONE barrier per 64-k
// with counted vmcnt(3) (zA' prefetch stays in flight across the barrier);
// per-half P buffers; setprio around MFMA clusters; ones-MFMA row sums;
// max-free softmax (exp2, scale pre-folded); pos diagonal gather via __shfl.
// ---------------------------------------------------------------------------
__global__ __launch_bounds__(256, 4) void attn_kernel(
    const __bf16* __restrict__ qu, const __bf16* __restrict__ qv,
    const __bf16* __restrict__ kk, const __bf16* __restrict__ vt,
    const __bf16* __restrict__ phZ,
    __bf16* __restrict__ ctx)
{
  __shared__ __align__(16) __bf16 kv_lds[4][2][1024];  // [buf][K|V][32x32]
  __shared__ __align__(16) __bf16 at_all[4][2][16 * 40];

  const int tid = threadIdx.x;
  const int wid = tid >> 6;
  const int l = tid & 63;
  const int lm = l & 15, lg = l >> 4;

  const int bid = blockIdx.x;               // [0, 1024)
  const int bh = (bid & 7) + 8 * ((bid >> 3) & 7);  // bh resident on XCD bid&7
  const int q0 = (bid >> 6) * 64 + wid * 16;
  const int h = bh & (H - 1), b = bh >> 4;

  const __bf16* qub = qu + (size_t)bh * S * Dh;
  const __bf16* qvb = qv + (size_t)bh * S * Dh;
  const __bf16* kb  = kk + (size_t)bh * S * Dh;
  const __bf16* vtb = vt + (size_t)bh * Dh * S;
  const __bf16* pZb = phZ + (size_t)bh * ZROWS * Dh;
  const __bf16* pAb = pZb + (size_t)(S + 1) * Dh;   // pA[m] = Z[S+1+m]

  const bf16x8 au  = *(const bf16x8*)(qub + (size_t)(q0 + lm) * Dh + lg * 8);
  const bf16x8 avA = *(const bf16x8*)(qvb + (size_t)(q0 + lm) * Dh + lg * 8);
  // row q+1 for the pB term; one-past reads hit allocated memory and are
  // multiplied by pB rows that are exactly zero wherever consumed.
  const bf16x8 avB = *(const bf16x8*)(qvb + (size_t)(q0 + 1 + lm) * Dh + lg * 8);

  int  slr[4];
  bool prd[4];
#pragma unroll
  for (int r = 0; r < 4; ++r) {
    const int qr = lg * 4 + r;
    slr[r] = (l & 48) | ((lm - qr + 15) & 15);
    prd[r] = (lm <= qr);
  }

  bf16x8 ones8;
#pragma unroll
  for (int i = 0; i < 8; ++i) ones8[i] = (__bf16)1.0f;

  f32x4 cta = {0.f,0.f,0.f,0.f}, ctb = {0.f,0.f,0.f,0.f};
  f32x4 ls  = {0.f,0.f,0.f,0.f};
  const f32x4 zero4 = {0.f,0.f,0.f,0.f};

  const int srow = l >> 2;
  const int scg  = ((l & 3) ^ (srow & 3)) * 8;
  auto stage = [&](int kt, int buf) {
    const __bf16* src;
    if (wid == 0)      src = kb  + (size_t)(kt + srow) * Dh + scg;
    else if (wid == 1) src = kb  + (size_t)(kt + 16 + srow) * Dh + scg;
    else if (wid == 2) src = vtb + (size_t)srow * S + kt + scg;
    else               src = vtb + (size_t)(16 + srow) * S + kt + scg;
    gload_lds16(src, &kv_lds[buf][wid >> 1][(wid & 1) * 512]);
  };

  const int cc = (lg ^ (lm & 3)) * 8;

  // Z-window prefetch into a named register set (3 tiles of 16 rows).
  auto zwin = [&](int kt, bf16x8& z0, bf16x8& z1, bf16x8& z2, bool& uB) {
    const int ktc = (kt < S) ? kt : (S - 32);
    uB = (ktc > q0 - 31);
    const int mb = ktc - q0 + (S - 16);
    const __bf16* zb = uB ? pZb : pAb;
    z0 = *(const bf16x8*)(zb + (size_t)(mb + lm) * Dh + lg * 8);
    z1 = *(const bf16x8*)(zb + (size_t)(mb + 16 + lm) * Dh + lg * 8);
    z2 = *(const bf16x8*)(zb + (size_t)(mb + 32 + lm) * Dh + lg * 8);
  };

  // One 32-k tile using a resident Z register set.
  auto half = [&](int kt, int tb, __bf16* at,
                  bf16x8 z0, bf16x8 z1, bf16x8 z2, bool uB) {
    const __bf16* Ks = kv_lds[tb][0];
    const __bf16* Vs = kv_lds[tb][1];
    bf16x8 kf0 = *(const bf16x8*)(Ks + lm * 32 + cc);
    bf16x8 kf1 = *(const bf16x8*)(Ks + (lm + 16) * 32 + cc);
    __builtin_amdgcn_s_setprio(1);
    f32x4 c0 = MFMA16(au, kf0, zero4);
    f32x4 c1 = MFMA16(au, kf1, zero4);
    const bf16x8 av = uB ? avB : avA;
    f32x4 pt0 = MFMA16(av, z0, zero4);
    f32x4 pt1 = MFMA16(av, z1, zero4);
    f32x4 pt2 = MFMA16(av, z2, zero4);
    __builtin_amdgcn_s_setprio(0);
    if (uB && (kt < q0 + 16)) {   // diagonal band (once per wave): add pA term
      const int mb = kt - q0 + (S - 16);
      bf16x8 y0 = *(const bf16x8*)(pAb + (size_t)(mb + lm) * Dh + lg * 8);
      bf16x8 y1 = *(const bf16x8*)(pAb + (size_t)(mb + 16 + lm) * Dh + lg * 8);
      bf16x8 y2 = *(const bf16x8*)(pAb + (size_t)(mb + 32 + lm) * Dh + lg * 8);
      pt0 = MFMA16(avA, y0, pt0);
      pt1 = MFMA16(avA, y1, pt1);
      pt2 = MFMA16(avA, y2, pt2);
    }

#pragma unroll
    for (int r = 0; r < 4; ++r) {
      const float v0 = __shfl(pt0[r], slr[r], 64);
      const float v1 = __shfl(pt1[r], slr[r], 64);
      const float v2 = __shfl(pt2[r], slr[r], 64);
      const float s0 = c0[r] + (prd[r] ? v0 : v1);
      const float s1 = c1[r] + (prd[r] ? v1 : v2);
      bf16x2 pp;
      pp[0] = (__bf16)fexp2(s0);             // k-col kt+lm     -> pos 2*lm
      pp[1] = (__bf16)fexp2(s1);             // k-col kt+16+lm  -> pos 2*lm+1
      *(bf16x2*)(at + (lg * 4 + r) * 40 + 2 * lm) = pp;
    }

    bf16x8 af  = *(const bf16x8*)(at + lm * 40 + lg * 8);
    bf16x8 vf0 = *(const bf16x8*)(Vs + lm * 32 + cc);
    bf16x8 vf1 = *(const bf16x8*)(Vs + (lm + 16) * 32 + cc);
    __builtin_amdgcn_s_setprio(1);
    cta = MFMA16(af, vf0, cta);
    ctb = MFMA16(af, vf1, ctb);
    ls  = MFMA16(af, ones8, ls);
    __builtin_amdgcn_s_setprio(0);
  };

  __bf16* at0 = at_all[wid][0];
  __bf16* at1 = at_all[wid][1];

  // ---- prologue: Z(0) + stage tiles 0,1.
  bf16x8 zA0, zA1, zA2, zB0, zB1, zB2;
  bool uA, uB;
  zwin(0, zA0, zA1, zA2, uA);
  stage(0, 0);
  stage(32, 1);
  asm volatile("s_waitcnt vmcnt(0)" ::: "memory");
  __builtin_amdgcn_s_barrier();

  for (int kt = 0; kt < S; kt += 64) {
    const int t = kt >> 5;
    // issue next-64k stages first (oldest in vmcnt order -> full-body slack)
    stage((kt + 64 < S) ? kt + 64 : kt, (t + 2) & 3);
    stage((kt + 96 < S) ? kt + 96 : kt, (t + 3) & 3);
    // zB for this iter's half B
    zwin(kt + 32, zB0, zB1, zB2, uB);
    // half A (consumes zA)
    half(kt, t & 3, at0, zA0, zA1, zA2, uA);
    // zA' for next iter's half A (stays in flight across the barrier)
    zwin(kt + 64, zA0, zA1, zA2, uA);
    // half B (consumes zB; its first use forces vmcnt(3) -> stages done)
    half(kt + 32, (t + 1) & 3, at1, zB0, zB1, zB2, uB);

    asm volatile("s_waitcnt vmcnt(3)" ::: "memory");
    __builtin_amdgcn_s_barrier();
  }

  // ---- normalize + store ctx (ls[r] = row sum, identical across lm lanes)
#pragma unroll
  for (int r = 0; r < 4; ++r) {
    const int s0 = q0 + lg * 4 + r;
    const float inv = 1.f / ls[r];
    __bf16* cp = ctx + ((size_t)b * S + s0) * DIM + h * Dh;
    cp[lm]      = (__bf16)(cta[r] * inv);
    cp[16 + lm] = (__bf16)(ctb[r] * inv);
  }
}

// ---------------------------------------------------------------------------
extern "C" void kernel_launch(void* const* d_in, const int* in_sizes, int n_in,
                              void* d_out, int out_size, void* d_ws, size_t ws_size,
                              hipStream_t stream) {
  const float* query = (const float*)d_in[0];
  const float* key   = (const float*)d_in[1];
  const float* value = (const float*)d_in[2];
  const float* pos   = (const float*)d_in[3];
  const float* Wq = (const float*)d_in[4];
  const float* bq = (const float*)d_in[5];
  const float* Wk = (const float*)d_in[6];
  const float* bk = (const float*)d_in[7];
  const float* Wv = (const float*)d_in[8];
  const float* bv = (const float*)d_in[9];
  const float* Wp = (const float*)d_in[10];
  const float* ub = (const float*)d_in[11];
  const float* vb = (const float*)d_in[12];
  const float* Wo = (const float*)d_in[13];
  const float* bo = (const float*)d_in[14];
  float* out = (float*)d_out;

  char* ws = (char*)d_ws;
  const size_t MB = 1ull << 20;
  // Layout:
  //   [ 0,16) MB : xb (4x bf16 activations)
  //   [16,18.5)  : wb (5x bf16 weights)
  //   [19,23)    : qu   [23,27): qv   [27,31): kk   [31,35): vt
  //   [35,47.7)  : phZ [B*H, 3S+16, 32]
  //   [48,52)    : ctx bf16
  __bf16* xb  = (__bf16*)(ws + 0 * MB);
  __bf16* wb  = (__bf16*)(ws + 16 * MB);
  __bf16* qu  = (__bf16*)(ws + 19 * MB);
  __bf16* qv  = (__bf16*)(ws + 23 * MB);
  __bf16* kk  = (__bf16*)(ws + 27 * MB);
  __bf16* vt  = (__bf16*)(ws + 31 * MB);
  __bf16* phZ = (__bf16*)(ws + 35 * MB);
  __bf16* ctx = (__bf16*)(ws + 48 * MB);

  conv_kernel<<<dim3(1024, 13), dim3(256), 0, stream>>>(
      query, key, value, pos, Wq, Wk, Wv, Wp, Wo, xb, wb, phZ);

  gemm_kernel<<<dim3(512), dim3(256), 0, stream>>>(
      xb, wb, ctx, bq, bk, bv, bo, ub, vb,
      qu, qv, kk, vt, phZ, out, 0);

  attn_kernel<<<dim3(1024), dim3(256), 0, stream>>>(
      qu, qv, kk, vt, phZ, ctx);

  gemm_kernel<<<dim3(128), dim3(256), 0, stream>>>(
      xb, wb, ctx, bq, bk, bv, bo, ub, vb,
      qu, qv, kk, vt, phZ, out, 1);
}

// Round 14
// 89.277 us; speedup vs baseline: 1.1636x; 1.0711x over previous
//
#include <hip/hip_runtime.h>
#include <hip/hip_bf16.h>
#include <math.h>

// Transformer-XL relative multi-head attention, bf16 MFMA implementation.
// B=4, S=1024, H=16, Dh=32, DIM=512.
//
// relative_shift identity: shifted[q,k] = qv[q]·pA[m] + qv[q+1]·pB[m],
// m = k - q + S - 1;  pA[m]=Z[S+1+m], pB[m]=Z[m] with a single zero-padded
// tensor Z (rows [S+1, 2S+1) = p, all else 0).
//
// Round 14 (attn at its floor ~46.5us -> pivot to the other ~49us):
//  * gemm z=2 (V^T) epilogue was a scalar-2B HBM scatter + interleave math.
//    Now: acc -> LDS (reusing As/Bs, chunk-XOR swizzle) -> coalesced b128
//    stores. The V k-interleave is dropped everywhere (attn P-store becomes
//    two b16 stores; PV slot order stays consistent).
//  * phZ zero-fill shrunk to the only rows ever read as zeros:
//    [960,1032) u [2040,2104) per bh = 0.56 MB (was 12.7 MB).
//  * outproj (mode 1) retiled to BM=64 -> grid 256 (was 128 = 0.5 block/CU).
//  * attn unchanged from R13.

typedef float f32x4 __attribute__((ext_vector_type(4)));
typedef __bf16 bf16x8 __attribute__((ext_vector_type(8)));
typedef __bf16 bf16x4 __attribute__((ext_vector_type(4)));

#define MFMA16(a, b, c) __builtin_amdgcn_mfma_f32_16x16x32_bf16((a), (b), (c), 0, 0, 0)

constexpr int Bb  = 4;
constexpr int S   = 1024;
constexpr int H   = 16;
constexpr int Dh  = 32;
constexpr int DIM = 512;
// 1/sqrt(32) * log2(e): scores come out pre-scaled for v_exp_f32 (=2^x).
constexpr float SCALEL2E = 0.25501818637084186f;
constexpr int ZROWS = 3 * S + 16;              // phZ rows per (b,h)

constexpr size_t XN = (size_t)Bb * S * DIM;   // elems per activation tensor
constexpr size_t WN = (size_t)DIM * DIM;      // elems per weight matrix

__device__ inline bf16x8 cvt8(const float* __restrict__ p) {
  f32x4 a = *(const f32x4*)p;
  f32x4 b = *(const f32x4*)(p + 4);
  bf16x8 r;
  r[0] = (__bf16)a[0]; r[1] = (__bf16)a[1]; r[2] = (__bf16)a[2]; r[3] = (__bf16)a[3];
  r[4] = (__bf16)b[0]; r[5] = (__bf16)b[1]; r[6] = (__bf16)b[2]; r[7] = (__bf16)b[3];
  return r;
}

__device__ inline float fexp2(float x) {
  float r;
  asm("v_exp_f32 %0, %1" : "=v"(r) : "v"(x));
  return r;
}

__device__ inline void gload_lds16(const __bf16* g, __bf16* l) {
  __builtin_amdgcn_global_load_lds(
      (const __attribute__((address_space(1))) unsigned int*)g,
      (__attribute__((address_space(3))) unsigned int*)l, 16, 0, 0);
}

// ---------------------------------------------------------------------------
// Kernel 0: f32 -> bf16 conversion (y=0..8) + phZ zero bands (y=9).
// ---------------------------------------------------------------------------
__global__ __launch_bounds__(256) void conv_kernel(
    const float* __restrict__ q, const float* __restrict__ k,
    const float* __restrict__ v, const float* __restrict__ p,
    const float* __restrict__ wq, const float* __restrict__ wk,
    const float* __restrict__ wv, const float* __restrict__ wp,
    const float* __restrict__ wo,
    __bf16* __restrict__ xb, __bf16* __restrict__ wb,
    __bf16* __restrict__ phZ)
{
  const int y = blockIdx.y;
  if (y == 9) {
    // zero only the bands the attn kernel ever reads as zeros:
    // rows [960,1032) and [2040,2104) per bh (p rows overwrite the overlap).
    const int e8 = blockIdx.x * 256 + threadIdx.x;
    if (e8 < 64 * 136 * 4) {
      const int rowIdx = e8 >> 2, chunk = e8 & 3;
      const int bh = rowIdx / 136;
      const int rl = rowIdx - bh * 136;
      const int row = (rl < 72) ? (960 + rl) : (2040 + (rl - 72));
      bf16x8 zz = {};
      *(bf16x8*)(phZ + ((size_t)bh * ZROWS + row) * Dh + chunk * 8) = zz;
    }
    return;
  }
  const float* src;
  size_t n;
  __bf16* dst;
  if (y < 4) {
    src = (y == 0) ? q : (y == 1) ? k : (y == 2) ? v : p;
    n = XN;
    dst = xb + (size_t)y * XN;
  } else {
    const int w = y - 4;
    src = (w == 0) ? wq : (w == 1) ? wk : (w == 2) ? wv : (w == 3) ? wp : wo;
    n = WN;
    dst = wb + (size_t)w * WN;
  }
  const size_t i = ((size_t)blockIdx.x * 256 + threadIdx.x) * 8;
  if (i >= n) return;
  *(bf16x8*)(dst + i) = cvt8(src + i);
}

// ---------------------------------------------------------------------------
// Kernel 1: tiled bf16 GEMM  C[M, N=512] = A @ B^T, K=512.
// MODE 0: BM=128, z=0..3 projections (grid 512).
// MODE 1: BM=64,  z=4 outproj (grid 256 -> 2x occupancy of the old 128).
// BK=64, 4 waves, global_load_lds(16B), XOR-swizzled source+read.
// z=2 writes V^T via an LDS transpose (coalesced b128 stores, no scatter).
// ---------------------------------------------------------------------------
template <int MODE>
__global__ __launch_bounds__(256) void gemm_kernel(
    const __bf16* __restrict__ xb, const __bf16* __restrict__ wb,
    const __bf16* __restrict__ ctxp,
    const float* __restrict__ bq, const float* __restrict__ bk,
    const float* __restrict__ bv, const float* __restrict__ bo,
    const float* __restrict__ ub, const float* __restrict__ vb,
    __bf16* __restrict__ qu, __bf16* __restrict__ qv,
    __bf16* __restrict__ kk, __bf16* __restrict__ vt,
    __bf16* __restrict__ phZ,
    float* __restrict__ outp)
{
  constexpr int MR = (MODE == 0) ? 4 : 2;     // m-frags per wave
  constexpr int BM = MR * 32;                 // block M-tile
  __shared__ __align__(16) __bf16 smem[BM * 64 + 128 * 64];
  __bf16* As = smem;                 // [BM x 64]
  __bf16* Bs = smem + BM * 64;       // [128 x 64]
  __bf16* trans = smem;              // z=2 epilogue: [128 d][128 s] (16K elems)

  const int bid = blockIdx.x;
  const int u = bid >> 3;
  const int by = u & 3;
  const int idx = (bid & 7) + 8 * (u >> 2);
  int bx, z;
  if (MODE == 0) { bx = idx & 31; z = idx >> 5; }
  else           { bx = idx;      z = 4; }

  const __bf16* Ag = (z < 4) ? (xb + (size_t)z * XN) : ctxp;
  const __bf16* Bg = wb + (size_t)z * WN;

  const int tid = threadIdx.x;
  const int wid = tid >> 6;
  const int ln = tid & 63;
  const int lm = ln & 15, lg = ln >> 4;
  const int wr = wid >> 1, wc = wid & 1;
  const int brow = bx * BM;
  const int bcol = by * 128;

  const int srow = ln >> 3;
  const int sc   = ln & 7;

  f32x4 acc[MR][4] = {};

  for (int kt = 0; kt < DIM / 64; ++kt) {
    const int k0 = kt * 64;
#pragma unroll
    for (int i = 0; i < MR; ++i) {            // A: BM rows
      const int rb = wid * (MR * 8) + i * 8;
      const int r = rb + srow;
      const int cg = sc ^ (r & 7);
      gload_lds16(Ag + (size_t)(brow + r) * DIM + k0 + cg * 8, &As[rb * 64]);
    }
#pragma unroll
    for (int i = 0; i < 4; ++i) {             // B: 128 rows
      const int rb = wid * 32 + i * 8;
      const int r = rb + srow;
      const int cg = sc ^ (r & 7);
      gload_lds16(Bg + (size_t)(bcol + r) * DIM + k0 + cg * 8, &Bs[rb * 64]);
    }
    __syncthreads();

#pragma unroll
    for (int ks = 0; ks < 2; ++ks) {
      bf16x8 a[MR], b[4];
#pragma unroll
      for (int m = 0; m < MR; ++m) {
        const int row = wr * (MR * 16) + m * 16 + lm;
        const int cc = (ks * 4 + lg) ^ (row & 7);
        a[m] = *(const bf16x8*)&As[row * 64 + cc * 8];
      }
#pragma unroll
      for (int n = 0; n < 4; ++n) {
        const int row = wc * 64 + n * 16 + lm;
        const int cc = (ks * 4 + lg) ^ (row & 7);
        b[n] = *(const bf16x8*)&Bs[row * 64 + cc * 8];
      }
#pragma unroll
      for (int m = 0; m < MR; ++m)
#pragma unroll
        for (int n = 0; n < 4; ++n)
          acc[m][n] = MFMA16(a[m], b[n], acc[m][n]);
    }
    __syncthreads();
  }

  // ---- epilogue
  if (MODE == 0 && z == 2) {
    // V^T via LDS transpose: acc -> trans[d][s] (chunk-XOR swizzled, no pad),
    // then coalesced b128 stores to vt[(bh*32+d)*S + s].
    const int b = brow >> 10;
    const int sbase = brow & (S - 1);
#pragma unroll
    for (int n = 0; n < 4; ++n) {
      const int dl = wc * 64 + n * 16 + lm;          // 0..127
      const float bias = bv[bcol + dl];
#pragma unroll
      for (int m = 0; m < 4; ++m) {
        const int sl = wr * 64 + m * 16 + lg * 4;    // aligned 4
        bf16x4 pk;
#pragma unroll
        for (int r = 0; r < 4; ++r) pk[r] = (__bf16)(acc[m][n][r] + bias);
        const int base = dl * 128 + (((sl >> 3) ^ (dl & 15)) * 8) + (sl & 7);
        *(bf16x4*)(trans + base) = pk;
      }
    }
    __syncthreads();
#pragma unroll
    for (int j = 0; j < 4; ++j) {
      const int dl = (tid >> 3) + j * 32;            // 0..127
      const int d = dl & 31, hl = dl >> 5;
      const int cp = (tid & 7) * 2;                  // chunk pair (16 elems)
      bf16x8 v0 = *(const bf16x8*)(trans + dl * 128 + ((cp ^ (dl & 15)) * 8));
      bf16x8 v1 = *(const bf16x8*)(trans + dl * 128 + (((cp + 1) ^ (dl & 15)) * 8));
      const int bh2 = b * H + (bcol >> 5) + hl;
      __bf16* dst = vt + ((size_t)bh2 * Dh + d) * S + sbase + cp * 8;
      *(bf16x8*)dst = v0;
      *(bf16x8*)(dst + 8) = v1;
    }
    return;
  }

#pragma unroll
  for (int n = 0; n < 4; ++n) {
    const int o = bcol + wc * 64 + n * 16 + lm;
    float bias = 0.f, ubv = 0.f, vbv = 0.f;
    if (z == 0) { bias = bq[o]; ubv = ub[o]; vbv = vb[o]; }
    else if (z == 1) bias = bk[o];
    else if (z == 4) bias = bo[o];
    const int h = o >> 5, d = o & 31;
#pragma unroll
    for (int m = 0; m < MR; ++m) {
#pragma unroll
      for (int r = 0; r < 4; ++r) {
        const int M = brow + wr * (MR * 16) + m * 16 + lg * 4 + r;
        const float val = acc[m][n][r];
        if (z == 4) {
          outp[(size_t)M * DIM + o] = val + bias;
          continue;
        }
        const int b = M >> 10, s = M & (S - 1);
        const int bh = b * H + h;
        if (z == 0) {
          // 1/sqrt(Dh)*log2(e) folded in (scores feed v_exp_f32 directly).
          const size_t idx2 = ((size_t)bh * S + s) * Dh + d;
          qu[idx2] = (__bf16)((val + bias + ubv) * SCALEL2E);
          qv[idx2] = (__bf16)((val + bias + vbv) * SCALEL2E);
        } else if (z == 1) {
          kk[((size_t)bh * S + s) * Dh + d] = (__bf16)(val + bias);
        } else {
          // phZ rows [S+1, 2S+1) = p; zero bands pre-filled by conv.
          phZ[((size_t)bh * ZROWS + (S + 1 + s)) * Dh + d] = (__bf16)val;
        }
      }
    }
  }
}

// ---------------------------------------------------------------------------
// Kernel 2: fused attention (R13 structure; V^T now s-linear -> P stored as
// two b16 per r). 256-thread blocks, 4 waves x 16 q-rows, grid 1024.
// K/V staged 2 64-k groups ahead in 4 LDS buffers (XOR-swizzled); Z windows
// register-double-buffered; ONE barrier per 64-k with counted vmcnt(3);
// per-half P buffers; setprio around MFMA; ones-MFMA row sums; max-free
// softmax (exp2, scale pre-folded); pos diagonal gather via __shfl.
// ---------------------------------------------------------------------------
__global__ __launch_bounds__(256, 4) void attn_kernel(
    const __bf16* __restrict__ qu, const __bf16* __restrict__ qv,
    const __bf16* __restrict__ kk, const __bf16* __restrict__ vt,
    const __bf16* __restrict__ phZ,
    __bf16* __restrict__ ctx)
{
  __shared__ __align__(16) __bf16 kv_lds[4][2][1024];  // [buf][K|V][32x32]
  __shared__ __align__(16) __bf16 at_all[4][2][16 * 40];

  const int tid = threadIdx.x;
  const int wid = tid >> 6;
  const int l = tid & 63;
  const int lm = l & 15, lg = l >> 4;

  const int bid = blockIdx.x;               // [0, 1024)
  const int bh = (bid & 7) + 8 * ((bid >> 3) & 7);  // bh resident on XCD bid&7
  const int q0 = (bid >> 6) * 64 + wid * 16;
  const int h = bh & (H - 1), b = bh >> 4;

  const __bf16* qub = qu + (size_t)bh * S * Dh;
  const __bf16* qvb = qv + (size_t)bh * S * Dh;
  const __bf16* kb  = kk + (size_t)bh * S * Dh;
  const __bf16* vtb = vt + (size_t)bh * Dh * S;
  const __bf16* pZb = phZ + (size_t)bh * ZROWS * Dh;
  const __bf16* pAb = pZb + (size_t)(S + 1) * Dh;   // pA[m] = Z[S+1+m]

  const bf16x8 au  = *(const bf16x8*)(qub + (size_t)(q0 + lm) * Dh + lg * 8);
  const bf16x8 avA = *(const bf16x8*)(qvb + (size_t)(q0 + lm) * Dh + lg * 8);
  // row q+1 for the pB term; one-past reads hit allocated memory and are
  // multiplied by pB rows that are exactly zero wherever consumed.
  const bf16x8 avB = *(const bf16x8*)(qvb + (size_t)(q0 + 1 + lm) * Dh + lg * 8);

  int  slr[4];
  bool prd[4];
#pragma unroll
  for (int r = 0; r < 4; ++r) {
    const int qr = lg * 4 + r;
    slr[r] = (l & 48) | ((lm - qr + 15) & 15);
    prd[r] = (lm <= qr);
  }

  bf16x8 ones8;
#pragma unroll
  for (int i = 0; i < 8; ++i) ones8[i] = (__bf16)1.0f;

  f32x4 cta = {0.f,0.f,0.f,0.f}, ctb = {0.f,0.f,0.f,0.f};
  f32x4 ls  = {0.f,0.f,0.f,0.f};
  const f32x4 zero4 = {0.f,0.f,0.f,0.f};

  const int srow = l >> 2;
  const int scg  = ((l & 3) ^ (srow & 3)) * 8;
  auto stage = [&](int kt, int buf) {
    const __bf16* src;
    if (wid == 0)      src = kb  + (size_t)(kt + srow) * Dh + scg;
    else if (wid == 1) src = kb  + (size_t)(kt + 16 + srow) * Dh + scg;
    else if (wid == 2) src = vtb + (size_t)srow * S + kt + scg;
    else               src = vtb + (size_t)(16 + srow) * S + kt + scg;
    gload_lds16(src, &kv_lds[buf][wid >> 1][(wid & 1) * 512]);
  };

  const int cc = (lg ^ (lm & 3)) * 8;

  // Z-window prefetch into a named register set (3 tiles of 16 rows).
  auto zwin = [&](int kt, bf16x8& z0, bf16x8& z1, bf16x8& z2, bool& uB) {
    const int ktc = (kt < S) ? kt : (S - 32);
    uB = (ktc > q0 - 31);
    const int mb = ktc - q0 + (S - 16);
    const __bf16* zb = uB ? pZb : pAb;
    z0 = *(const bf16x8*)(zb + (size_t)(mb + lm) * Dh + lg * 8);
    z1 = *(const bf16x8*)(zb + (size_t)(mb + 16 + lm) * Dh + lg * 8);
    z2 = *(const bf16x8*)(zb + (size_t)(mb + 32 + lm) * Dh + lg * 8);
  };

  // One 32-k tile using a resident Z register set.
  auto half = [&](int kt, int tb, __bf16* at,
                  bf16x8 z0, bf16x8 z1, bf16x8 z2, bool uB) {
    const __bf16* Ks = kv_lds[tb][0];
    const __bf16* Vs = kv_lds[tb][1];
    bf16x8 kf0 = *(const bf16x8*)(Ks + lm * 32 + cc);
    bf16x8 kf1 = *(const bf16x8*)(Ks + (lm + 16) * 32 + cc);
    __builtin_amdgcn_s_setprio(1);
    f32x4 c0 = MFMA16(au, kf0, zero4);
    f32x4 c1 = MFMA16(au, kf1, zero4);
    const bf16x8 av = uB ? avB : avA;
    f32x4 pt0 = MFMA16(av, z0, zero4);
    f32x4 pt1 = MFMA16(av, z1, zero4);
    f32x4 pt2 = MFMA16(av, z2, zero4);
    __builtin_amdgcn_s_setprio(0);
    if (uB && (kt < q0 + 16)) {   // diagonal band (once per wave): add pA term
      const int mb = kt - q0 + (S - 16);
      bf16x8 y0 = *(const bf16x8*)(pAb + (size_t)(mb + lm) * Dh + lg * 8);
      bf16x8 y1 = *(const bf16x8*)(pAb + (size_t)(mb + 16 + lm) * Dh + lg * 8);
      bf16x8 y2 = *(const bf16x8*)(pAb + (size_t)(mb + 32 + lm) * Dh + lg * 8);
      pt0 = MFMA16(avA, y0, pt0);
      pt1 = MFMA16(avA, y1, pt1);
      pt2 = MFMA16(avA, y2, pt2);
    }

#pragma unroll
    for (int r = 0; r < 4; ++r) {
      const float v0 = __shfl(pt0[r], slr[r], 64);
      const float v1 = __shfl(pt1[r], slr[r], 64);
      const float v2 = __shfl(pt2[r], slr[r], 64);
      const float s0 = c0[r] + (prd[r] ? v0 : v1);
      const float s1 = c1[r] + (prd[r] ? v1 : v2);
      // V^T is s-linear now: slot lm = col kt+lm, slot 16+lm = col kt+16+lm.
      at[(lg * 4 + r) * 40 + lm]      = (__bf16)fexp2(s0);
      at[(lg * 4 + r) * 40 + 16 + lm] = (__bf16)fexp2(s1);
    }

    bf16x8 af  = *(const bf16x8*)(at + lm * 40 + lg * 8);
    bf16x8 vf0 = *(const bf16x8*)(Vs + lm * 32 + cc);
    bf16x8 vf1 = *(const bf16x8*)(Vs + (lm + 16) * 32 + cc);
    __builtin_amdgcn_s_setprio(1);
    cta = MFMA16(af, vf0, cta);
    ctb = MFMA16(af, vf1, ctb);
    ls  = MFMA16(af, ones8, ls);
    __builtin_amdgcn_s_setprio(0);
  };

  __bf16* at0 = at_all[wid][0];
  __bf16* at1 = at_all[wid][1];

  // ---- prologue: Z(0) + stage tiles 0,1.
  bf16x8 zA0, zA1, zA2, zB0, zB1, zB2;
  bool uA, uB;
  zwin(0, zA0, zA1, zA2, uA);
  stage(0, 0);
  stage(32, 1);
  asm volatile("s_waitcnt vmcnt(0)" ::: "memory");
  __builtin_amdgcn_s_barrier();

  for (int kt = 0; kt < S; kt += 64) {
    const int t = kt >> 5;
    // issue next-64k stages first (oldest in vmcnt order -> full-body slack)
    stage((kt + 64 < S) ? kt + 64 : kt, (t + 2) & 3);
    stage((kt + 96 < S) ? kt + 96 : kt, (t + 3) & 3);
    // zB for this iter's half B
    zwin(kt + 32, zB0, zB1, zB2, uB);
    // half A (consumes zA)
    half(kt, t & 3, at0, zA0, zA1, zA2, uA);
    // zA' for next iter's half A (stays in flight across the barrier)
    zwin(kt + 64, zA0, zA1, zA2, uA);
    // half B (consumes zB; its first use forces vmcnt(3) -> stages done)
    half(kt + 32, (t + 1) & 3, at1, zB0, zB1, zB2, uB);

    asm volatile("s_waitcnt vmcnt(3)" ::: "memory");
    __builtin_amdgcn_s_barrier();
  }

  // ---- normalize + store ctx (ls[r] = row sum, identical across lm lanes)
#pragma unroll
  for (int r = 0; r < 4; ++r) {
    const int s0 = q0 + lg * 4 + r;
    const float inv = 1.f / ls[r];
    __bf16* cp = ctx + ((size_t)b * S + s0) * DIM + h * Dh;
    cp[lm]      = (__bf16)(cta[r] * inv);
    cp[16 + lm] = (__bf16)(ctb[r] * inv);
  }
}

// ---------------------------------------------------------------------------
extern "C" void kernel_launch(void* const* d_in, const int* in_sizes, int n_in,
                              void* d_out, int out_size, void* d_ws, size_t ws_size,
                              hipStream_t stream) {
  const float* query = (const float*)d_in[0];
  const float* key   = (const float*)d_in[1];
  const float* value = (const float*)d_in[2];
  const float* pos   = (const float*)d_in[3];
  const float* Wq = (const float*)d_in[4];
  const float* bq = (const float*)d_in[5];
  const float* Wk = (const float*)d_in[6];
  const float* bk = (const float*)d_in[7];
  const float* Wv = (const float*)d_in[8];
  const float* bv = (const float*)d_in[9];
  const float* Wp = (const float*)d_in[10];
  const float* ub = (const float*)d_in[11];
  const float* vb = (const float*)d_in[12];
  const float* Wo = (const float*)d_in[13];
  const float* bo = (const float*)d_in[14];
  float* out = (float*)d_out;

  char* ws = (char*)d_ws;
  const size_t MB = 1ull << 20;
  // Layout:
  //   [ 0,16) MB : xb (4x bf16 activations)
  //   [16,18.5)  : wb (5x bf16 weights)
  //   [19,23)    : qu   [23,27): qv   [27,31): kk   [31,35): vt
  //   [35,47.7)  : phZ [B*H, 3S+16, 32]
  //   [48,52)    : ctx bf16
  __bf16* xb  = (__bf16*)(ws + 0 * MB);
  __bf16* wb  = (__bf16*)(ws + 16 * MB);
  __bf16* qu  = (__bf16*)(ws + 19 * MB);
  __bf16* qv  = (__bf16*)(ws + 23 * MB);
  __bf16* kk  = (__bf16*)(ws + 27 * MB);
  __bf16* vt  = (__bf16*)(ws + 31 * MB);
  __bf16* phZ = (__bf16*)(ws + 35 * MB);
  __bf16* ctx = (__bf16*)(ws + 48 * MB);

  conv_kernel<<<dim3(1024, 10), dim3(256), 0, stream>>>(
      query, key, value, pos, Wq, Wk, Wv, Wp, Wo, xb, wb, phZ);

  gemm_kernel<0><<<dim3(512), dim3(256), 0, stream>>>(
      xb, wb, ctx, bq, bk, bv, bo, ub, vb,
      qu, qv, kk, vt, phZ, out);

  attn_kernel<<<dim3(1024), dim3(256), 0, stream>>>(
      qu, qv, kk, vt, phZ, ctx);

  gemm_kernel<1><<<dim3(256), dim3(256), 0, stream>>>(
      xb, wb, ctx, bq, bk, bv, bo, ub, vb,
      qu, qv, kk, vt, phZ, out);
}

// Round 15
// 84.209 us; speedup vs baseline: 1.2337x; 1.0602x over previous
//
#include <hip/hip_runtime.h>
#include <hip/hip_bf16.h>
#include <math.h>

// Transformer-XL relative multi-head attention, bf16 MFMA implementation.
// B=4, S=1024, H=16, Dh=32, DIM=512.
//
// relative_shift identity: shifted[q,k] = qv[q]·pA[m] + qv[q+1]·pB[m],
// m = k - q + S - 1;  pA[m]=Z[S+1+m], pB[m]=Z[m] with a single zero-padded
// tensor Z (rows [S+1, 2S+1) = p, all else 0).
//
// Round 15: combine R13's attn (46.4us floor: packed b32 P-stores with
// k-interleaved V^T) with R14's gemm epilogue wins. The V^T k-interleave is
// RESTORED globally; gemm z=2 still writes it via the LDS-transpose +
// coalesced b128 stores: interleaving pairs (s, s+16) -> slots (2t, 2t+1),
// and both values sit in one lane's adjacent m-frags (acc[2mp], acc[2mp+1])
// -> 32 packed bf16x2 LDS writes, no scatter. Everything else = R14.

typedef float f32x4 __attribute__((ext_vector_type(4)));
typedef __bf16 bf16x8 __attribute__((ext_vector_type(8)));
typedef __bf16 bf16x2 __attribute__((ext_vector_type(2)));

#define MFMA16(a, b, c) __builtin_amdgcn_mfma_f32_16x16x32_bf16((a), (b), (c), 0, 0, 0)

constexpr int Bb  = 4;
constexpr int S   = 1024;
constexpr int H   = 16;
constexpr int Dh  = 32;
constexpr int DIM = 512;
// 1/sqrt(32) * log2(e): scores come out pre-scaled for v_exp_f32 (=2^x).
constexpr float SCALEL2E = 0.25501818637084186f;
constexpr int ZROWS = 3 * S + 16;              // phZ rows per (b,h)

constexpr size_t XN = (size_t)Bb * S * DIM;   // elems per activation tensor
constexpr size_t WN = (size_t)DIM * DIM;      // elems per weight matrix

__device__ inline bf16x8 cvt8(const float* __restrict__ p) {
  f32x4 a = *(const f32x4*)p;
  f32x4 b = *(const f32x4*)(p + 4);
  bf16x8 r;
  r[0] = (__bf16)a[0]; r[1] = (__bf16)a[1]; r[2] = (__bf16)a[2]; r[3] = (__bf16)a[3];
  r[4] = (__bf16)b[0]; r[5] = (__bf16)b[1]; r[6] = (__bf16)b[2]; r[7] = (__bf16)b[3];
  return r;
}

__device__ inline float fexp2(float x) {
  float r;
  asm("v_exp_f32 %0, %1" : "=v"(r) : "v"(x));
  return r;
}

__device__ inline void gload_lds16(const __bf16* g, __bf16* l) {
  __builtin_amdgcn_global_load_lds(
      (const __attribute__((address_space(1))) unsigned int*)g,
      (__attribute__((address_space(3))) unsigned int*)l, 16, 0, 0);
}

// ---------------------------------------------------------------------------
// Kernel 0: f32 -> bf16 conversion (y=0..8) + phZ zero bands (y=9).
// ---------------------------------------------------------------------------
__global__ __launch_bounds__(256) void conv_kernel(
    const float* __restrict__ q, const float* __restrict__ k,
    const float* __restrict__ v, const float* __restrict__ p,
    const float* __restrict__ wq, const float* __restrict__ wk,
    const float* __restrict__ wv, const float* __restrict__ wp,
    const float* __restrict__ wo,
    __bf16* __restrict__ xb, __bf16* __restrict__ wb,
    __bf16* __restrict__ phZ)
{
  const int y = blockIdx.y;
  if (y == 9) {
    // zero only the bands the attn kernel ever reads as zeros:
    // rows [960,1032) and [2040,2104) per bh (p rows overwrite the overlap).
    const int e8 = blockIdx.x * 256 + threadIdx.x;
    if (e8 < 64 * 136 * 4) {
      const int rowIdx = e8 >> 2, chunk = e8 & 3;
      const int bh = rowIdx / 136;
      const int rl = rowIdx - bh * 136;
      const int row = (rl < 72) ? (960 + rl) : (2040 + (rl - 72));
      bf16x8 zz = {};
      *(bf16x8*)(phZ + ((size_t)bh * ZROWS + row) * Dh + chunk * 8) = zz;
    }
    return;
  }
  const float* src;
  size_t n;
  __bf16* dst;
  if (y < 4) {
    src = (y == 0) ? q : (y == 1) ? k : (y == 2) ? v : p;
    n = XN;
    dst = xb + (size_t)y * XN;
  } else {
    const int w = y - 4;
    src = (w == 0) ? wq : (w == 1) ? wk : (w == 2) ? wv : (w == 3) ? wp : wo;
    n = WN;
    dst = wb + (size_t)w * WN;
  }
  const size_t i = ((size_t)blockIdx.x * 256 + threadIdx.x) * 8;
  if (i >= n) return;
  *(bf16x8*)(dst + i) = cvt8(src + i);
}

// ---------------------------------------------------------------------------
// Kernel 1: tiled bf16 GEMM  C[M, N=512] = A @ B^T, K=512.
// MODE 0: BM=128, z=0..3 projections (grid 512).
// MODE 1: BM=64,  z=4 outproj (grid 256).
// BK=64, 4 waves, global_load_lds(16B), XOR-swizzled source+read.
// z=2 writes k-interleaved V^T via LDS transpose: interleave pairs (s,s+16)
// -> slots (2t,2t+1) live in one lane's adjacent m-frags -> packed bf16x2
// LDS writes + coalesced b128 global stores.
// ---------------------------------------------------------------------------
template <int MODE>
__global__ __launch_bounds__(256) void gemm_kernel(
    const __bf16* __restrict__ xb, const __bf16* __restrict__ wb,
    const __bf16* __restrict__ ctxp,
    const float* __restrict__ bq, const float* __restrict__ bk,
    const float* __restrict__ bv, const float* __restrict__ bo,
    const float* __restrict__ ub, const float* __restrict__ vb,
    __bf16* __restrict__ qu, __bf16* __restrict__ qv,
    __bf16* __restrict__ kk, __bf16* __restrict__ vt,
    __bf16* __restrict__ phZ,
    float* __restrict__ outp)
{
  constexpr int MR = (MODE == 0) ? 4 : 2;     // m-frags per wave
  constexpr int BM = MR * 32;                 // block M-tile
  __shared__ __align__(16) __bf16 smem[BM * 64 + 128 * 64];
  __bf16* As = smem;                 // [BM x 64]
  __bf16* Bs = smem + BM * 64;       // [128 x 64]
  __bf16* trans = smem;              // z=2 epilogue: [128 d][128 s] (16K elems)

  const int bid = blockIdx.x;
  const int u = bid >> 3;
  const int by = u & 3;
  const int idx = (bid & 7) + 8 * (u >> 2);
  int bx, z;
  if (MODE == 0) { bx = idx & 31; z = idx >> 5; }
  else           { bx = idx;      z = 4; }

  const __bf16* Ag = (z < 4) ? (xb + (size_t)z * XN) : ctxp;
  const __bf16* Bg = wb + (size_t)z * WN;

  const int tid = threadIdx.x;
  const int wid = tid >> 6;
  const int ln = tid & 63;
  const int lm = ln & 15, lg = ln >> 4;
  const int wr = wid >> 1, wc = wid & 1;
  const int brow = bx * BM;
  const int bcol = by * 128;

  const int srow = ln >> 3;
  const int sc   = ln & 7;

  f32x4 acc[MR][4] = {};

  for (int kt = 0; kt < DIM / 64; ++kt) {
    const int k0 = kt * 64;
#pragma unroll
    for (int i = 0; i < MR; ++i) {            // A: BM rows
      const int rb = wid * (MR * 8) + i * 8;
      const int r = rb + srow;
      const int cg = sc ^ (r & 7);
      gload_lds16(Ag + (size_t)(brow + r) * DIM + k0 + cg * 8, &As[rb * 64]);
    }
#pragma unroll
    for (int i = 0; i < 4; ++i) {             // B: 128 rows
      const int rb = wid * 32 + i * 8;
      const int r = rb + srow;
      const int cg = sc ^ (r & 7);
      gload_lds16(Bg + (size_t)(bcol + r) * DIM + k0 + cg * 8, &Bs[rb * 64]);
    }
    __syncthreads();

#pragma unroll
    for (int ks = 0; ks < 2; ++ks) {
      bf16x8 a[MR], b[4];
#pragma unroll
      for (int m = 0; m < MR; ++m) {
        const int row = wr * (MR * 16) + m * 16 + lm;
        const int cc = (ks * 4 + lg) ^ (row & 7);
        a[m] = *(const bf16x8*)&As[row * 64 + cc * 8];
      }
#pragma unroll
      for (int n = 0; n < 4; ++n) {
        const int row = wc * 64 + n * 16 + lm;
        const int cc = (ks * 4 + lg) ^ (row & 7);
        b[n] = *(const bf16x8*)&Bs[row * 64 + cc * 8];
      }
#pragma unroll
      for (int m = 0; m < MR; ++m)
#pragma unroll
        for (int n = 0; n < 4; ++n)
          acc[m][n] = MFMA16(a[m], b[n], acc[m][n]);
    }
    __syncthreads();
  }

  // ---- epilogue
  if (MODE == 0 && z == 2) {
    // k-interleaved V^T via LDS transpose. Within each 32-s-block, actual
    // columns (s, s+16) -> storage slots (2t, 2t+1), t = s&15. Both values
    // are in this lane's acc[2mp][n][r] / acc[2mp+1][n][r] -> bf16x2 writes.
    const int b = brow >> 10;
    const int sbase = brow & (S - 1);
#pragma unroll
    for (int n = 0; n < 4; ++n) {
      const int dl = wc * 64 + n * 16 + lm;          // 0..127
      const float bias = bv[bcol + dl];
#pragma unroll
      for (int mp = 0; mp < 2; ++mp) {
#pragma unroll
        for (int r = 0; r < 4; ++r) {
          const int p = wr * 64 + mp * 32 + 2 * (lg * 4 + r);  // even slot
          bf16x2 pk;
          pk[0] = (__bf16)(acc[2 * mp][n][r] + bias);      // col s
          pk[1] = (__bf16)(acc[2 * mp + 1][n][r] + bias);  // col s+16
          const int base = dl * 128 + (((p >> 3) ^ (dl & 15)) * 8) + (p & 7);
          *(bf16x2*)(trans + base) = pk;
        }
      }
    }
    __syncthreads();
#pragma unroll
    for (int j = 0; j < 4; ++j) {
      const int dl = (tid >> 3) + j * 32;            // 0..127
      const int d = dl & 31, hl = dl >> 5;
      const int cp = (tid & 7) * 2;                  // chunk pair (16 elems)
      bf16x8 v0 = *(const bf16x8*)(trans + dl * 128 + ((cp ^ (dl & 15)) * 8));
      bf16x8 v1 = *(const bf16x8*)(trans + dl * 128 + (((cp + 1) ^ (dl & 15)) * 8));
      const int bh2 = b * H + (bcol >> 5) + hl;
      __bf16* dst = vt + ((size_t)bh2 * Dh + d) * S + sbase + cp * 8;
      *(bf16x8*)dst = v0;
      *(bf16x8*)(dst + 8) = v1;
    }
    return;
  }

#pragma unroll
  for (int n = 0; n < 4; ++n) {
    const int o = bcol + wc * 64 + n * 16 + lm;
    float bias = 0.f, ubv = 0.f, vbv = 0.f;
    if (z == 0) { bias = bq[o]; ubv = ub[o]; vbv = vb[o]; }
    else if (z == 1) bias = bk[o];
    else if (z == 4) bias = bo[o];
    const int h = o >> 5, d = o & 31;
#pragma unroll
    for (int m = 0; m < MR; ++m) {
#pragma unroll
      for (int r = 0; r < 4; ++r) {
        const int M = brow + wr * (MR * 16) + m * 16 + lg * 4 + r;
        const float val = acc[m][n][r];
        if (z == 4) {
          outp[(size_t)M * DIM + o] = val + bias;
          continue;
        }
        const int b = M >> 10, s = M & (S - 1);
        const int bh = b * H + h;
        if (z == 0) {
          // 1/sqrt(Dh)*log2(e) folded in (scores feed v_exp_f32 directly).
          const size_t idx2 = ((size_t)bh * S + s) * Dh + d;
          qu[idx2] = (__bf16)((val + bias + ubv) * SCALEL2E);
          qv[idx2] = (__bf16)((val + bias + vbv) * SCALEL2E);
        } else if (z == 1) {
          kk[((size_t)bh * S + s) * Dh + d] = (__bf16)(val + bias);
        } else {
          // phZ rows [S+1, 2S+1) = p; zero bands pre-filled by conv.
          phZ[((size_t)bh * ZROWS + (S + 1 + s)) * Dh + d] = (__bf16)val;
        }
      }
    }
  }
}

// ---------------------------------------------------------------------------
// Kernel 2: fused attention (R13 body verbatim: packed b32 P-stores matching
// the k-interleaved V^T). 256-thread blocks, 4 waves x 16 q-rows, grid 1024.
// K/V staged 2 64-k groups ahead in 4 LDS buffers (XOR-swizzled); Z windows
// register-double-buffered; ONE barrier per 64-k with counted vmcnt(3);
// per-half P buffers; setprio around MFMA; ones-MFMA row sums; max-free
// softmax (exp2, scale pre-folded); pos diagonal gather via __shfl.
// ---------------------------------------------------------------------------
__global__ __launch_bounds__(256, 4) void attn_kernel(
    const __bf16* __restrict__ qu, const __bf16* __restrict__ qv,
    const __bf16* __restrict__ kk, const __bf16* __restrict__ vt,
    const __bf16* __restrict__ phZ,
    __bf16* __restrict__ ctx)
{
  __shared__ __align__(16) __bf16 kv_lds[4][2][1024];  // [buf][K|V][32x32]
  __shared__ __align__(16) __bf16 at_all[4][2][16 * 40];

  const int tid = threadIdx.x;
  const int wid = tid >> 6;
  const int l = tid & 63;
  const int lm = l & 15, lg = l >> 4;

  const int bid = blockIdx.x;               // [0, 1024)
  const int bh = (bid & 7) + 8 * ((bid >> 3) & 7);  // bh resident on XCD bid&7
  const int q0 = (bid >> 6) * 64 + wid * 16;
  const int h = bh & (H - 1), b = bh >> 4;

  const __bf16* qub = qu + (size_t)bh * S * Dh;
  const __bf16* qvb = qv + (size_t)bh * S * Dh;
  const __bf16* kb  = kk + (size_t)bh * S * Dh;
  const __bf16* vtb = vt + (size_t)bh * Dh * S;
  const __bf16* pZb = phZ + (size_t)bh * ZROWS * Dh;
  const __bf16* pAb = pZb + (size_t)(S + 1) * Dh;   // pA[m] = Z[S+1+m]

  const bf16x8 au  = *(const bf16x8*)(qub + (size_t)(q0 + lm) * Dh + lg * 8);
  const bf16x8 avA = *(const bf16x8*)(qvb + (size_t)(q0 + lm) * Dh + lg * 8);
  // row q+1 for the pB term; one-past reads hit allocated memory and are
  // multiplied by pB rows that are exactly zero wherever consumed.
  const bf16x8 avB = *(const bf16x8*)(qvb + (size_t)(q0 + 1 + lm) * Dh + lg * 8);

  int  slr[4];
  bool prd[4];
#pragma unroll
  for (int r = 0; r < 4; ++r) {
    const int qr = lg * 4 + r;
    slr[r] = (l & 48) | ((lm - qr + 15) & 15);
    prd[r] = (lm <= qr);
  }

  bf16x8 ones8;
#pragma unroll
  for (int i = 0; i < 8; ++i) ones8[i] = (__bf16)1.0f;

  f32x4 cta = {0.f,0.f,0.f,0.f}, ctb = {0.f,0.f,0.f,0.f};
  f32x4 ls  = {0.f,0.f,0.f,0.f};
  const f32x4 zero4 = {0.f,0.f,0.f,0.f};

  const int srow = l >> 2;
  const int scg  = ((l & 3) ^ (srow & 3)) * 8;
  auto stage = [&](int kt, int buf) {
    const __bf16* src;
    if (wid == 0)      src = kb  + (size_t)(kt + srow) * Dh + scg;
    else if (wid == 1) src = kb  + (size_t)(kt + 16 + srow) * Dh + scg;
    else if (wid == 2) src = vtb + (size_t)srow * S + kt + scg;
    else               src = vtb + (size_t)(16 + srow) * S + kt + scg;
    gload_lds16(src, &kv_lds[buf][wid >> 1][(wid & 1) * 512]);
  };

  const int cc = (lg ^ (lm & 3)) * 8;

  // Z-window prefetch into a named register set (3 tiles of 16 rows).
  auto zwin = [&](int kt, bf16x8& z0, bf16x8& z1, bf16x8& z2, bool& uB) {
    const int ktc = (kt < S) ? kt : (S - 32);
    uB = (ktc > q0 - 31);
    const int mb = ktc - q0 + (S - 16);
    const __bf16* zb = uB ? pZb : pAb;
    z0 = *(const bf16x8*)(zb + (size_t)(mb + lm) * Dh + lg * 8);
    z1 = *(const bf16x8*)(zb + (size_t)(mb + 16 + lm) * Dh + lg * 8);
    z2 = *(const bf16x8*)(zb + (size_t)(mb + 32 + lm) * Dh + lg * 8);
  };

  // One 32-k tile using a resident Z register set.
  auto half = [&](int kt, int tb, __bf16* at,
                  bf16x8 z0, bf16x8 z1, bf16x8 z2, bool uB) {
    const __bf16* Ks = kv_lds[tb][0];
    const __bf16* Vs = kv_lds[tb][1];
    bf16x8 kf0 = *(const bf16x8*)(Ks + lm * 32 + cc);
    bf16x8 kf1 = *(const bf16x8*)(Ks + (lm + 16) * 32 + cc);
    __builtin_amdgcn_s_setprio(1);
    f32x4 c0 = MFMA16(au, kf0, zero4);
    f32x4 c1 = MFMA16(au, kf1, zero4);
    const bf16x8 av = uB ? avB : avA;
    f32x4 pt0 = MFMA16(av, z0, zero4);
    f32x4 pt1 = MFMA16(av, z1, zero4);
    f32x4 pt2 = MFMA16(av, z2, zero4);
    __builtin_amdgcn_s_setprio(0);
    if (uB && (kt < q0 + 16)) {   // diagonal band (once per wave): add pA term
      const int mb = kt - q0 + (S - 16);
      bf16x8 y0 = *(const bf16x8*)(pAb + (size_t)(mb + lm) * Dh + lg * 8);
      bf16x8 y1 = *(const bf16x8*)(pAb + (size_t)(mb + 16 + lm) * Dh + lg * 8);
      bf16x8 y2 = *(const bf16x8*)(pAb + (size_t)(mb + 32 + lm) * Dh + lg * 8);
      pt0 = MFMA16(avA, y0, pt0);
      pt1 = MFMA16(avA, y1, pt1);
      pt2 = MFMA16(avA, y2, pt2);
    }

#pragma unroll
    for (int r = 0; r < 4; ++r) {
      const float v0 = __shfl(pt0[r], slr[r], 64);
      const float v1 = __shfl(pt1[r], slr[r], 64);
      const float v2 = __shfl(pt2[r], slr[r], 64);
      const float s0 = c0[r] + (prd[r] ? v0 : v1);
      const float s1 = c1[r] + (prd[r] ? v1 : v2);
      bf16x2 pp;
      pp[0] = (__bf16)fexp2(s0);             // k-col kt+lm     -> slot 2*lm
      pp[1] = (__bf16)fexp2(s1);             // k-col kt+16+lm  -> slot 2*lm+1
      *(bf16x2*)(at + (lg * 4 + r) * 40 + 2 * lm) = pp;
    }

    bf16x8 af  = *(const bf16x8*)(at + lm * 40 + lg * 8);
    bf16x8 vf0 = *(const bf16x8*)(Vs + lm * 32 + cc);
    bf16x8 vf1 = *(const bf16x8*)(Vs + (lm + 16) * 32 + cc);
    __builtin_amdgcn_s_setprio(1);
    cta = MFMA16(af, vf0, cta);
    ctb = MFMA16(af, vf1, ctb);
    ls  = MFMA16(af, ones8, ls);
    __builtin_amdgcn_s_setprio(0);
  };

  __bf16* at0 = at_all[wid][0];
  __bf16* at1 = at_all[wid][1];

  // ---- prologue: Z(0) + stage tiles 0,1.
  bf16x8 zA0, zA1, zA2, zB0, zB1, zB2;
  bool uA, uB;
  zwin(0, zA0, zA1, zA2, uA);
  stage(0, 0);
  stage(32, 1);
  asm volatile("s_waitcnt vmcnt(0)" ::: "memory");
  __builtin_amdgcn_s_barrier();

  for (int kt = 0; kt < S; kt += 64) {
    const int t = kt >> 5;
    // issue next-64k stages first (oldest in vmcnt order -> full-body slack)
    stage((kt + 64 < S) ? kt + 64 : kt, (t + 2) & 3);
    stage((kt + 96 < S) ? kt + 96 : kt, (t + 3) & 3);
    // zB for this iter's half B
    zwin(kt + 32, zB0, zB1, zB2, uB);
    // half A (consumes zA)
    half(kt, t & 3, at0, zA0, zA1, zA2, uA);
    // zA' for next iter's half A (stays in flight across the barrier)
    zwin(kt + 64, zA0, zA1, zA2, uA);
    // half B (consumes zB; its first use forces vmcnt(3) -> stages done)
    half(kt + 32, (t + 1) & 3, at1, zB0, zB1, zB2, uB);

    asm volatile("s_waitcnt vmcnt(3)" ::: "memory");
    __builtin_amdgcn_s_barrier();
  }

  // ---- normalize + store ctx (ls[r] = row sum, identical across lm lanes)
#pragma unroll
  for (int r = 0; r < 4; ++r) {
    const int s0 = q0 + lg * 4 + r;
    const float inv = 1.f / ls[r];
    __bf16* cp = ctx + ((size_t)b * S + s0) * DIM + h * Dh;
    cp[lm]      = (__bf16)(cta[r] * inv);
    cp[16 + lm] = (__bf16)(ctb[r] * inv);
  }
}

// ---------------------------------------------------------------------------
extern "C" void kernel_launch(void* const* d_in, const int* in_sizes, int n_in,
                              void* d_out, int out_size, void* d_ws, size_t ws_size,
                              hipStream_t stream) {
  const float* query = (const float*)d_in[0];
  const float* key   = (const float*)d_in[1];
  const float* value = (const float*)d_in[2];
  const float* pos   = (const float*)d_in[3];
  const float* Wq = (const float*)d_in[4];
  const float* bq = (const float*)d_in[5];
  const float* Wk = (const float*)d_in[6];
  const float* bk = (const float*)d_in[7];
  const float* Wv = (const float*)d_in[8];
  const float* bv = (const float*)d_in[9];
  const float* Wp = (const float*)d_in[10];
  const float* ub = (const float*)d_in[11];
  const float* vb = (const float*)d_in[12];
  const float* Wo = (const float*)d_in[13];
  const float* bo = (const float*)d_in[14];
  float* out = (float*)d_out;

  char* ws = (char*)d_ws;
  const size_t MB = 1ull << 20;
  // Layout:
  //   [ 0,16) MB : xb (4x bf16 activations)
  //   [16,18.5)  : wb (5x bf16 weights)
  //   [19,23)    : qu   [23,27): qv   [27,31): kk   [31,35): vt
  //   [35,47.7)  : phZ [B*H, 3S+16, 32]
  //   [48,52)    : ctx bf16
  __bf16* xb  = (__bf16*)(ws + 0 * MB);
  __bf16* wb  = (__bf16*)(ws + 16 * MB);
  __bf16* qu  = (__bf16*)(ws + 19 * MB);
  __bf16* qv  = (__bf16*)(ws + 23 * MB);
  __bf16* kk  = (__bf16*)(ws + 27 * MB);
  __bf16* vt  = (__bf16*)(ws + 31 * MB);
  __bf16* phZ = (__bf16*)(ws + 35 * MB);
  __bf16* ctx = (__bf16*)(ws + 48 * MB);

  conv_kernel<<<dim3(1024, 10), dim3(256), 0, stream>>>(
      query, key, value, pos, Wq, Wk, Wv, Wp, Wo, xb, wb, phZ);

  gemm_kernel<0><<<dim3(512), dim3(256), 0, stream>>>(
      xb, wb, ctx, bq, bk, bv, bo, ub, vb,
      qu, qv, kk, vt, phZ, out);

  attn_kernel<<<dim3(1024), dim3(256), 0, stream>>>(
      qu, qv, kk, vt, phZ, ctx);

  gemm_kernel<1><<<dim3(256), dim3(256), 0, stream>>>(
      xb, wb, ctx, bq, bk, bv, bo, ub, vb,
      qu, qv, kk, vt, phZ, out);
}

// Round 16
// 82.795 us; speedup vs baseline: 1.2547x; 1.0171x over previous
//
#include <hip/hip_runtime.h>
#include <hip/hip_bf16.h>
#include <math.h>

// Transformer-XL relative multi-head attention, bf16 MFMA implementation.
// B=4, S=1024, H=16, Dh=32, DIM=512.
//
// relative_shift identity: shifted[q,k] = qv[q]·pA[m] + qv[q+1]·pB[m],
// m = k - q + S - 1;  pA[m]=Z[S+1+m], pB[m]=Z[m] with a single zero-padded
// tensor Z (rows [S+1, 2S+1) = p, all else 0).
//
// Round 16 (attn LDS-pipe reduction; gemm/conv = R15):
//  * K/V LDS swizzle upgraded: s(row)=(row>>1)&3 (was row&3). Old scheme left
//    lanes lm, lm+4, lm+8, lm+12 on identical bank quads -> 4-way conflict
//    (1.58x per m136); new scheme gives exact 2-way (free). Applied on both
//    stage source and read (rule #21).
//  * Z-window register reuse: window(kt+32) tile0 == window(kt) tile2 and
//    next window tile0 == zB2 -> 6 Z loads/iter -> 4. Explicit load only at
//    the once-per-wave pA/pB base transition. Barrier vmcnt recounted to 3.

typedef float f32x4 __attribute__((ext_vector_type(4)));
typedef __bf16 bf16x8 __attribute__((ext_vector_type(8)));
typedef __bf16 bf16x2 __attribute__((ext_vector_type(2)));

#define MFMA16(a, b, c) __builtin_amdgcn_mfma_f32_16x16x32_bf16((a), (b), (c), 0, 0, 0)

constexpr int Bb  = 4;
constexpr int S   = 1024;
constexpr int H   = 16;
constexpr int Dh  = 32;
constexpr int DIM = 512;
// 1/sqrt(32) * log2(e): scores come out pre-scaled for v_exp_f32 (=2^x).
constexpr float SCALEL2E = 0.25501818637084186f;
constexpr int ZROWS = 3 * S + 16;              // phZ rows per (b,h)

constexpr size_t XN = (size_t)Bb * S * DIM;   // elems per activation tensor
constexpr size_t WN = (size_t)DIM * DIM;      // elems per weight matrix

__device__ inline bf16x8 cvt8(const float* __restrict__ p) {
  f32x4 a = *(const f32x4*)p;
  f32x4 b = *(const f32x4*)(p + 4);
  bf16x8 r;
  r[0] = (__bf16)a[0]; r[1] = (__bf16)a[1]; r[2] = (__bf16)a[2]; r[3] = (__bf16)a[3];
  r[4] = (__bf16)b[0]; r[5] = (__bf16)b[1]; r[6] = (__bf16)b[2]; r[7] = (__bf16)b[3];
  return r;
}

__device__ inline float fexp2(float x) {
  float r;
  asm("v_exp_f32 %0, %1" : "=v"(r) : "v"(x));
  return r;
}

__device__ inline void gload_lds16(const __bf16* g, __bf16* l) {
  __builtin_amdgcn_global_load_lds(
      (const __attribute__((address_space(1))) unsigned int*)g,
      (__attribute__((address_space(3))) unsigned int*)l, 16, 0, 0);
}

// ---------------------------------------------------------------------------
// Kernel 0: f32 -> bf16 conversion (y=0..8) + phZ zero bands (y=9).
// ---------------------------------------------------------------------------
__global__ __launch_bounds__(256) void conv_kernel(
    const float* __restrict__ q, const float* __restrict__ k,
    const float* __restrict__ v, const float* __restrict__ p,
    const float* __restrict__ wq, const float* __restrict__ wk,
    const float* __restrict__ wv, const float* __restrict__ wp,
    const float* __restrict__ wo,
    __bf16* __restrict__ xb, __bf16* __restrict__ wb,
    __bf16* __restrict__ phZ)
{
  const int y = blockIdx.y;
  if (y == 9) {
    // zero only the bands the attn kernel ever reads as zeros:
    // rows [960,1032) and [2040,2104) per bh (p rows overwrite the overlap).
    const int e8 = blockIdx.x * 256 + threadIdx.x;
    if (e8 < 64 * 136 * 4) {
      const int rowIdx = e8 >> 2, chunk = e8 & 3;
      const int bh = rowIdx / 136;
      const int rl = rowIdx - bh * 136;
      const int row = (rl < 72) ? (960 + rl) : (2040 + (rl - 72));
      bf16x8 zz = {};
      *(bf16x8*)(phZ + ((size_t)bh * ZROWS + row) * Dh + chunk * 8) = zz;
    }
    return;
  }
  const float* src;
  size_t n;
  __bf16* dst;
  if (y < 4) {
    src = (y == 0) ? q : (y == 1) ? k : (y == 2) ? v : p;
    n = XN;
    dst = xb + (size_t)y * XN;
  } else {
    const int w = y - 4;
    src = (w == 0) ? wq : (w == 1) ? wk : (w == 2) ? wv : (w == 3) ? wp : wo;
    n = WN;
    dst = wb + (size_t)w * WN;
  }
  const size_t i = ((size_t)blockIdx.x * 256 + threadIdx.x) * 8;
  if (i >= n) return;
  *(bf16x8*)(dst + i) = cvt8(src + i);
}

// ---------------------------------------------------------------------------
// Kernel 1: tiled bf16 GEMM  C[M, N=512] = A @ B^T, K=512.
// MODE 0: BM=128, z=0..3 projections (grid 512).
// MODE 1: BM=64,  z=4 outproj (grid 256).
// BK=64, 4 waves, global_load_lds(16B), XOR-swizzled source+read.
// z=2 writes k-interleaved V^T via LDS transpose (packed bf16x2 writes +
// coalesced b128 global stores).
// ---------------------------------------------------------------------------
template <int MODE>
__global__ __launch_bounds__(256) void gemm_kernel(
    const __bf16* __restrict__ xb, const __bf16* __restrict__ wb,
    const __bf16* __restrict__ ctxp,
    const float* __restrict__ bq, const float* __restrict__ bk,
    const float* __restrict__ bv, const float* __restrict__ bo,
    const float* __restrict__ ub, const float* __restrict__ vb,
    __bf16* __restrict__ qu, __bf16* __restrict__ qv,
    __bf16* __restrict__ kk, __bf16* __restrict__ vt,
    __bf16* __restrict__ phZ,
    float* __restrict__ outp)
{
  constexpr int MR = (MODE == 0) ? 4 : 2;     // m-frags per wave
  constexpr int BM = MR * 32;                 // block M-tile
  __shared__ __align__(16) __bf16 smem[BM * 64 + 128 * 64];
  __bf16* As = smem;                 // [BM x 64]
  __bf16* Bs = smem + BM * 64;       // [128 x 64]
  __bf16* trans = smem;              // z=2 epilogue: [128 d][128 s]

  const int bid = blockIdx.x;
  const int u = bid >> 3;
  const int by = u & 3;
  const int idx = (bid & 7) + 8 * (u >> 2);
  int bx, z;
  if (MODE == 0) { bx = idx & 31; z = idx >> 5; }
  else           { bx = idx;      z = 4; }

  const __bf16* Ag = (z < 4) ? (xb + (size_t)z * XN) : ctxp;
  const __bf16* Bg = wb + (size_t)z * WN;

  const int tid = threadIdx.x;
  const int wid = tid >> 6;
  const int ln = tid & 63;
  const int lm = ln & 15, lg = ln >> 4;
  const int wr = wid >> 1, wc = wid & 1;
  const int brow = bx * BM;
  const int bcol = by * 128;

  const int srow = ln >> 3;
  const int sc   = ln & 7;

  f32x4 acc[MR][4] = {};

  for (int kt = 0; kt < DIM / 64; ++kt) {
    const int k0 = kt * 64;
#pragma unroll
    for (int i = 0; i < MR; ++i) {            // A: BM rows
      const int rb = wid * (MR * 8) + i * 8;
      const int r = rb + srow;
      const int cg = sc ^ (r & 7);
      gload_lds16(Ag + (size_t)(brow + r) * DIM + k0 + cg * 8, &As[rb * 64]);
    }
#pragma unroll
    for (int i = 0; i < 4; ++i) {             // B: 128 rows
      const int rb = wid * 32 + i * 8;
      const int r = rb + srow;
      const int cg = sc ^ (r & 7);
      gload_lds16(Bg + (size_t)(bcol + r) * DIM + k0 + cg * 8, &Bs[rb * 64]);
    }
    __syncthreads();

#pragma unroll
    for (int ks = 0; ks < 2; ++ks) {
      bf16x8 a[MR], b[4];
#pragma unroll
      for (int m = 0; m < MR; ++m) {
        const int row = wr * (MR * 16) + m * 16 + lm;
        const int cc = (ks * 4 + lg) ^ (row & 7);
        a[m] = *(const bf16x8*)&As[row * 64 + cc * 8];
      }
#pragma unroll
      for (int n = 0; n < 4; ++n) {
        const int row = wc * 64 + n * 16 + lm;
        const int cc = (ks * 4 + lg) ^ (row & 7);
        b[n] = *(const bf16x8*)&Bs[row * 64 + cc * 8];
      }
#pragma unroll
      for (int m = 0; m < MR; ++m)
#pragma unroll
        for (int n = 0; n < 4; ++n)
          acc[m][n] = MFMA16(a[m], b[n], acc[m][n]);
    }
    __syncthreads();
  }

  // ---- epilogue
  if (MODE == 0 && z == 2) {
    // k-interleaved V^T via LDS transpose. Within each 32-s-block, actual
    // columns (s, s+16) -> storage slots (2t, 2t+1), t = s&15. Both values
    // are in this lane's acc[2mp][n][r] / acc[2mp+1][n][r] -> bf16x2 writes.
    const int b = brow >> 10;
    const int sbase = brow & (S - 1);
#pragma unroll
    for (int n = 0; n < 4; ++n) {
      const int dl = wc * 64 + n * 16 + lm;          // 0..127
      const float bias = bv[bcol + dl];
#pragma unroll
      for (int mp = 0; mp < 2; ++mp) {
#pragma unroll
        for (int r = 0; r < 4; ++r) {
          const int p = wr * 64 + mp * 32 + 2 * (lg * 4 + r);  // even slot
          bf16x2 pk;
          pk[0] = (__bf16)(acc[2 * mp][n][r] + bias);      // col s
          pk[1] = (__bf16)(acc[2 * mp + 1][n][r] + bias);  // col s+16
          const int base = dl * 128 + (((p >> 3) ^ (dl & 15)) * 8) + (p & 7);
          *(bf16x2*)(trans + base) = pk;
        }
      }
    }
    __syncthreads();
#pragma unroll
    for (int j = 0; j < 4; ++j) {
      const int dl = (tid >> 3) + j * 32;            // 0..127
      const int d = dl & 31, hl = dl >> 5;
      const int cp = (tid & 7) * 2;                  // chunk pair (16 elems)
      bf16x8 v0 = *(const bf16x8*)(trans + dl * 128 + ((cp ^ (dl & 15)) * 8));
      bf16x8 v1 = *(const bf16x8*)(trans + dl * 128 + (((cp + 1) ^ (dl & 15)) * 8));
      const int bh2 = b * H + (bcol >> 5) + hl;
      __bf16* dst = vt + ((size_t)bh2 * Dh + d) * S + sbase + cp * 8;
      *(bf16x8*)dst = v0;
      *(bf16x8*)(dst + 8) = v1;
    }
    return;
  }

#pragma unroll
  for (int n = 0; n < 4; ++n) {
    const int o = bcol + wc * 64 + n * 16 + lm;
    float bias = 0.f, ubv = 0.f, vbv = 0.f;
    if (z == 0) { bias = bq[o]; ubv = ub[o]; vbv = vb[o]; }
    else if (z == 1) bias = bk[o];
    else if (z == 4) bias = bo[o];
    const int h = o >> 5, d = o & 31;
#pragma unroll
    for (int m = 0; m < MR; ++m) {
#pragma unroll
      for (int r = 0; r < 4; ++r) {
        const int M = brow + wr * (MR * 16) + m * 16 + lg * 4 + r;
        const float val = acc[m][n][r];
        if (z == 4) {
          outp[(size_t)M * DIM + o] = val + bias;
          continue;
        }
        const int b = M >> 10, s = M & (S - 1);
        const int bh = b * H + h;
        if (z == 0) {
          // 1/sqrt(Dh)*log2(e) folded in (scores feed v_exp_f32 directly).
          const size_t idx2 = ((size_t)bh * S + s) * Dh + d;
          qu[idx2] = (__bf16)((val + bias + ubv) * SCALEL2E);
          qv[idx2] = (__bf16)((val + bias + vbv) * SCALEL2E);
        } else if (z == 1) {
          kk[((size_t)bh * S + s) * Dh + d] = (__bf16)(val + bias);
        } else {
          // phZ rows [S+1, 2S+1) = p; zero bands pre-filled by conv.
          phZ[((size_t)bh * ZROWS + (S + 1 + s)) * Dh + d] = (__bf16)val;
        }
      }
    }
  }
}

// ---------------------------------------------------------------------------
// Kernel 2: fused attention. 256-thread blocks, 4 waves x 16 q-rows, grid
// 1024. K/V staged 2 64-k groups ahead in 4 LDS buffers with 2-way-free
// XOR swizzle s(row)=(row>>1)&3; Z windows register-reused across halves
// (4 loads/iter); ONE barrier per 64-k with counted vmcnt(3); per-half P
// buffers (packed b32 stores, k-interleaved V^T); setprio around MFMA;
// ones-MFMA row sums; max-free softmax (exp2); pos gather via __shfl.
// ---------------------------------------------------------------------------
__global__ __launch_bounds__(256, 4) void attn_kernel(
    const __bf16* __restrict__ qu, const __bf16* __restrict__ qv,
    const __bf16* __restrict__ kk, const __bf16* __restrict__ vt,
    const __bf16* __restrict__ phZ,
    __bf16* __restrict__ ctx)
{
  __shared__ __align__(16) __bf16 kv_lds[4][2][1024];  // [buf][K|V][32x32]
  __shared__ __align__(16) __bf16 at_all[4][2][16 * 40];

  const int tid = threadIdx.x;
  const int wid = tid >> 6;
  const int l = tid & 63;
  const int lm = l & 15, lg = l >> 4;

  const int bid = blockIdx.x;               // [0, 1024)
  const int bh = (bid & 7) + 8 * ((bid >> 3) & 7);  // bh resident on XCD bid&7
  const int q0 = (bid >> 6) * 64 + wid * 16;
  const int h = bh & (H - 1), b = bh >> 4;

  const __bf16* qub = qu + (size_t)bh * S * Dh;
  const __bf16* qvb = qv + (size_t)bh * S * Dh;
  const __bf16* kb  = kk + (size_t)bh * S * Dh;
  const __bf16* vtb = vt + (size_t)bh * Dh * S;
  const __bf16* pZb = phZ + (size_t)bh * ZROWS * Dh;
  const __bf16* pAb = pZb + (size_t)(S + 1) * Dh;   // pA[m] = Z[S+1+m]

  const bf16x8 au  = *(const bf16x8*)(qub + (size_t)(q0 + lm) * Dh + lg * 8);
  const bf16x8 avA = *(const bf16x8*)(qvb + (size_t)(q0 + lm) * Dh + lg * 8);
  // row q+1 for the pB term; one-past reads hit allocated memory and are
  // multiplied by pB rows that are exactly zero wherever consumed.
  const bf16x8 avB = *(const bf16x8*)(qvb + (size_t)(q0 + 1 + lm) * Dh + lg * 8);

  int  slr[4];
  bool prd[4];
#pragma unroll
  for (int r = 0; r < 4; ++r) {
    const int qr = lg * 4 + r;
    slr[r] = (l & 48) | ((lm - qr + 15) & 15);
    prd[r] = (lm <= qr);
  }

  bf16x8 ones8;
#pragma unroll
  for (int i = 0; i < 8; ++i) ones8[i] = (__bf16)1.0f;

  f32x4 cta = {0.f,0.f,0.f,0.f}, ctb = {0.f,0.f,0.f,0.f};
  f32x4 ls  = {0.f,0.f,0.f,0.f};
  const f32x4 zero4 = {0.f,0.f,0.f,0.f};

  // staging: lane l writes 16B at linear offset l*16 in its wave's 1KB
  // quadrant (rows srow=l>>2, storage chunk l&3). Source chunk inverse-
  // swizzled with s(row) = (row>>1)&3  ->  ((l&3) ^ ((l>>3)&3)).
  const int srow = l >> 2;
  const int scg  = ((l & 3) ^ ((l >> 3) & 3)) * 8;
  auto stage = [&](int kt, int buf) {
    const __bf16* src;
    if (wid == 0)      src = kb  + (size_t)(kt + srow) * Dh + scg;
    else if (wid == 1) src = kb  + (size_t)(kt + 16 + srow) * Dh + scg;
    else if (wid == 2) src = vtb + (size_t)srow * S + kt + scg;
    else               src = vtb + (size_t)(16 + srow) * S + kt + scg;
    gload_lds16(src, &kv_lds[buf][wid >> 1][(wid & 1) * 512]);
  };

  // read chunk, same swizzle: rows lm and lm+16 share s = (lm>>1)&3.
  const int cc = (lg ^ ((lm >> 1) & 3)) * 8;

  // Z-window tile load: window(ktc) tile at +off (16-row tile), base uB_.
  auto zld = [&](int ktc, int off, bool uB_) -> bf16x8 {
    const int mb = ktc - q0 + (S - 16);
    const __bf16* zb = uB_ ? pZb : pAb;
    return *(const bf16x8*)(zb + (size_t)(mb + off + lm) * Dh + lg * 8);
  };

  // One 32-k tile using a resident Z register set.
  auto half = [&](int kt, int tb, __bf16* at,
                  bf16x8 z0, bf16x8 z1, bf16x8 z2, bool uB_) {
    const __bf16* Ks = kv_lds[tb][0];
    const __bf16* Vs = kv_lds[tb][1];
    bf16x8 kf0 = *(const bf16x8*)(Ks + lm * 32 + cc);
    bf16x8 kf1 = *(const bf16x8*)(Ks + (lm + 16) * 32 + cc);
    __builtin_amdgcn_s_setprio(1);
    f32x4 c0 = MFMA16(au, kf0, zero4);
    f32x4 c1 = MFMA16(au, kf1, zero4);
    const bf16x8 av = uB_ ? avB : avA;
    f32x4 pt0 = MFMA16(av, z0, zero4);
    f32x4 pt1 = MFMA16(av, z1, zero4);
    f32x4 pt2 = MFMA16(av, z2, zero4);
    __builtin_amdgcn_s_setprio(0);
    if (uB_ && (kt < q0 + 16)) {  // diagonal band (once per wave): add pA term
      const int mb = kt - q0 + (S - 16);
      bf16x8 y0 = *(const bf16x8*)(pAb + (size_t)(mb + lm) * Dh + lg * 8);
      bf16x8 y1 = *(const bf16x8*)(pAb + (size_t)(mb + 16 + lm) * Dh + lg * 8);
      bf16x8 y2 = *(const bf16x8*)(pAb + (size_t)(mb + 32 + lm) * Dh + lg * 8);
      pt0 = MFMA16(avA, y0, pt0);
      pt1 = MFMA16(avA, y1, pt1);
      pt2 = MFMA16(avA, y2, pt2);
    }

#pragma unroll
    for (int r = 0; r < 4; ++r) {
      const float v0 = __shfl(pt0[r], slr[r], 64);
      const float v1 = __shfl(pt1[r], slr[r], 64);
      const float v2 = __shfl(pt2[r], slr[r], 64);
      const float s0 = c0[r] + (prd[r] ? v0 : v1);
      const float s1 = c1[r] + (prd[r] ? v1 : v2);
      bf16x2 pp;
      pp[0] = (__bf16)fexp2(s0);             // k-col kt+lm     -> slot 2*lm
      pp[1] = (__bf16)fexp2(s1);             // k-col kt+16+lm  -> slot 2*lm+1
      *(bf16x2*)(at + (lg * 4 + r) * 40 + 2 * lm) = pp;
    }

    bf16x8 af  = *(const bf16x8*)(at + lm * 40 + lg * 8);
    bf16x8 vf0 = *(const bf16x8*)(Vs + lm * 32 + cc);
    bf16x8 vf1 = *(const bf16x8*)(Vs + (lm + 16) * 32 + cc);
    __builtin_amdgcn_s_setprio(1);
    cta = MFMA16(af, vf0, cta);
    ctb = MFMA16(af, vf1, ctb);
    ls  = MFMA16(af, ones8, ls);
    __builtin_amdgcn_s_setprio(0);
  };

  __bf16* at0 = at_all[wid][0];
  __bf16* at1 = at_all[wid][1];

  // ---- prologue: Z(0) + stage tiles 0,1.
  bf16x8 zA0, zA1, zA2;
  bool uA = (0 > q0 - 31);
  zA0 = zld(0, 0, uA);
  zA1 = zld(0, 16, uA);
  zA2 = zld(0, 32, uA);
  stage(0, 0);
  stage(32, 1);
  asm volatile("s_waitcnt vmcnt(0)" ::: "memory");
  __builtin_amdgcn_s_barrier();

  for (int kt = 0; kt < S; kt += 64) {
    const int t = kt >> 5;
    // next-64k stages first (oldest in vmcnt order -> full-body slack)
    stage((kt + 64 < S) ? kt + 64 : kt, (t + 2) & 3);
    stage((kt + 96 < S) ? kt + 96 : kt, (t + 3) & 3);

    // zB window (kt+32): tile0 == zA window tile2 when bases match.
    const bool uB = ((kt + 32) > q0 - 31);
    bf16x8 zB0;
    if (uB == uA) zB0 = zA2;
    else          zB0 = zld(kt + 32, 0, uB);
    bf16x8 zB1 = zld(kt + 32, 16, uB);
    bf16x8 zB2 = zld(kt + 32, 32, uB);

    half(kt, t & 3, at0, zA0, zA1, zA2, uA);

    // zA' window (kt+64): tiles 16,32 loaded directly (first use next iter);
    // tile0 == zB2 when bases match (copied after half B).
    const int ktn = (kt + 64 < S) ? kt + 64 : (S - 32);
    const bool uAn = (ktn > q0 - 31);
    zA1 = zld(ktn, 16, uAn);
    zA2 = zld(ktn, 32, uAn);

    half(kt + 32, (t + 1) & 3, at1, zB0, zB1, zB2, uB);

    if (uAn == uB) zA0 = zB2;
    else           zA0 = zld(ktn, 0, uAn);
    uA = uAn;

    asm volatile("s_waitcnt vmcnt(3)" ::: "memory");
    __builtin_amdgcn_s_barrier();
  }

  // ---- normalize + store ctx (ls[r] = row sum, identical across lm lanes)
#pragma unroll
  for (int r = 0; r < 4; ++r) {
    const int s0 = q0 + lg * 4 + r;
    const float inv = 1.f / ls[r];
    __bf16* cp = ctx + ((size_t)b * S + s0) * DIM + h * Dh;
    cp[lm]      = (__bf16)(cta[r] * inv);
    cp[16 + lm] = (__bf16)(ctb[r] * inv);
  }
}

// ---------------------------------------------------------------------------
extern "C" void kernel_launch(void* const* d_in, const int* in_sizes, int n_in,
                              void* d_out, int out_size, void* d_ws, size_t ws_size,
                              hipStream_t stream) {
  const float* query = (const float*)d_in[0];
  const float* key   = (const float*)d_in[1];
  const float* value = (const float*)d_in[2];
  const float* pos   = (const float*)d_in[3];
  const float* Wq = (const float*)d_in[4];
  const float* bq = (const float*)d_in[5];
  const float* Wk = (const float*)d_in[6];
  const float* bk = (const float*)d_in[7];
  const float* Wv = (const float*)d_in[8];
  const float* bv = (const float*)d_in[9];
  const float* Wp = (const float*)d_in[10];
  const float* ub = (const float*)d_in[11];
  const float* vb = (const float*)d_in[12];
  const float* Wo = (const float*)d_in[13];
  const float* bo = (const float*)d_in[14];
  float* out = (float*)d_out;

  char* ws = (char*)d_ws;
  const size_t MB = 1ull << 20;
  // Layout:
  //   [ 0,16) MB : xb (4x bf16 activations)
  //   [16,18.5)  : wb (5x bf16 weights)
  //   [19,23)    : qu   [23,27): qv   [27,31): kk   [31,35): vt
  //   [35,47.7)  : phZ [B*H, 3S+16, 32]
  //   [48,52)    : ctx bf16
  __bf16* xb  = (__bf16*)(ws + 0 * MB);
  __bf16* wb  = (__bf16*)(ws + 16 * MB);
  __bf16* qu  = (__bf16*)(ws + 19 * MB);
  __bf16* qv  = (__bf16*)(ws + 23 * MB);
  __bf16* kk  = (__bf16*)(ws + 27 * MB);
  __bf16* vt  = (__bf16*)(ws + 31 * MB);
  __bf16* phZ = (__bf16*)(ws + 35 * MB);
  __bf16* ctx = (__bf16*)(ws + 48 * MB);

  conv_kernel<<<dim3(1024, 10), dim3(256), 0, stream>>>(
      query, key, value, pos, Wq, Wk, Wv, Wp, Wo, xb, wb, phZ);

  gemm_kernel<0><<<dim3(512), dim3(256), 0, stream>>>(
      xb, wb, ctx, bq, bk, bv, bo, ub, vb,
      qu, qv, kk, vt, phZ, out);

  attn_kernel<<<dim3(1024), dim3(256), 0, stream>>>(
      qu, qv, kk, vt, phZ, ctx);

  gemm_kernel<1><<<dim3(256), dim3(256), 0, stream>>>(
      xb, wb, ctx, bq, bk, bv, bo, ub, vb,
      qu, qv, kk, vt, phZ, out);
}

// Round 17
// 82.139 us; speedup vs baseline: 1.2647x; 1.0080x over previous
//
#include <hip/hip_runtime.h>
#include <hip/hip_bf16.h>
#include <math.h>

// Transformer-XL relative multi-head attention, bf16 MFMA implementation.
// B=4, S=1024, H=16, Dh=32, DIM=512.
//
// relative_shift identity: shifted[q,k] = qv[q]·pA[m] + qv[q+1]·pB[m],
// m = k - q + S - 1;  pA[m]=Z[S+1+m], pB[m]=Z[m] with a single zero-padded
// tensor Z (rows [S+1, 2S+1) = p, all else 0).
//
// Round 17: gemm mode-0 retiled BM=128 -> 64 (MR=2), grid 512 -> 1024
// (2 -> 4 blocks/CU, 2 -> 4 waves/SIMD) — same under-occupancy fix that
// worked for outproj in R14. z=2 V^T epilogue re-derived for MR=2
// (pair = acc[0]/acc[1], slot p = wr*32+2t, trans [128][64]).
// attn (R16: 2-way-free swizzle, Z register reuse), conv, outproj unchanged.

typedef float f32x4 __attribute__((ext_vector_type(4)));
typedef __bf16 bf16x8 __attribute__((ext_vector_type(8)));
typedef __bf16 bf16x2 __attribute__((ext_vector_type(2)));

#define MFMA16(a, b, c) __builtin_amdgcn_mfma_f32_16x16x32_bf16((a), (b), (c), 0, 0, 0)

constexpr int Bb  = 4;
constexpr int S   = 1024;
constexpr int H   = 16;
constexpr int Dh  = 32;
constexpr int DIM = 512;
// 1/sqrt(32) * log2(e): scores come out pre-scaled for v_exp_f32 (=2^x).
constexpr float SCALEL2E = 0.25501818637084186f;
constexpr int ZROWS = 3 * S + 16;              // phZ rows per (b,h)

constexpr size_t XN = (size_t)Bb * S * DIM;   // elems per activation tensor
constexpr size_t WN = (size_t)DIM * DIM;      // elems per weight matrix

__device__ inline bf16x8 cvt8(const float* __restrict__ p) {
  f32x4 a = *(const f32x4*)p;
  f32x4 b = *(const f32x4*)(p + 4);
  bf16x8 r;
  r[0] = (__bf16)a[0]; r[1] = (__bf16)a[1]; r[2] = (__bf16)a[2]; r[3] = (__bf16)a[3];
  r[4] = (__bf16)b[0]; r[5] = (__bf16)b[1]; r[6] = (__bf16)b[2]; r[7] = (__bf16)b[3];
  return r;
}

__device__ inline float fexp2(float x) {
  float r;
  asm("v_exp_f32 %0, %1" : "=v"(r) : "v"(x));
  return r;
}

__device__ inline void gload_lds16(const __bf16* g, __bf16* l) {
  __builtin_amdgcn_global_load_lds(
      (const __attribute__((address_space(1))) unsigned int*)g,
      (__attribute__((address_space(3))) unsigned int*)l, 16, 0, 0);
}

// ---------------------------------------------------------------------------
// Kernel 0: f32 -> bf16 conversion (y=0..8) + phZ zero bands (y=9).
// ---------------------------------------------------------------------------
__global__ __launch_bounds__(256) void conv_kernel(
    const float* __restrict__ q, const float* __restrict__ k,
    const float* __restrict__ v, const float* __restrict__ p,
    const float* __restrict__ wq, const float* __restrict__ wk,
    const float* __restrict__ wv, const float* __restrict__ wp,
    const float* __restrict__ wo,
    __bf16* __restrict__ xb, __bf16* __restrict__ wb,
    __bf16* __restrict__ phZ)
{
  const int y = blockIdx.y;
  if (y == 9) {
    // zero only the bands the attn kernel ever reads as zeros:
    // rows [960,1032) and [2040,2104) per bh (p rows overwrite the overlap).
    const int e8 = blockIdx.x * 256 + threadIdx.x;
    if (e8 < 64 * 136 * 4) {
      const int rowIdx = e8 >> 2, chunk = e8 & 3;
      const int bh = rowIdx / 136;
      const int rl = rowIdx - bh * 136;
      const int row = (rl < 72) ? (960 + rl) : (2040 + (rl - 72));
      bf16x8 zz = {};
      *(bf16x8*)(phZ + ((size_t)bh * ZROWS + row) * Dh + chunk * 8) = zz;
    }
    return;
  }
  const float* src;
  size_t n;
  __bf16* dst;
  if (y < 4) {
    src = (y == 0) ? q : (y == 1) ? k : (y == 2) ? v : p;
    n = XN;
    dst = xb + (size_t)y * XN;
  } else {
    const int w = y - 4;
    src = (w == 0) ? wq : (w == 1) ? wk : (w == 2) ? wv : (w == 3) ? wp : wo;
    n = WN;
    dst = wb + (size_t)w * WN;
  }
  const size_t i = ((size_t)blockIdx.x * 256 + threadIdx.x) * 8;
  if (i >= n) return;
  *(bf16x8*)(dst + i) = cvt8(src + i);
}

// ---------------------------------------------------------------------------
// Kernel 1: tiled bf16 GEMM  C[M, N=512] = A @ B^T, K=512.
// Both modes: BM=64 (MR=2), 4 waves, BK=64, global_load_lds(16B),
// XOR-swizzled source+read.
// MODE 0: z=0..3 projections, grid 1024 (4 blocks/CU).
// MODE 1: z=4 outproj, grid 256.
// z=2 writes k-interleaved V^T via LDS transpose (packed bf16x2 writes +
// coalesced b128 global stores).
// ---------------------------------------------------------------------------
template <int MODE>
__global__ __launch_bounds__(256) void gemm_kernel(
    const __bf16* __restrict__ xb, const __bf16* __restrict__ wb,
    const __bf16* __restrict__ ctxp,
    const float* __restrict__ bq, const float* __restrict__ bk,
    const float* __restrict__ bv, const float* __restrict__ bo,
    const float* __restrict__ ub, const float* __restrict__ vb,
    __bf16* __restrict__ qu, __bf16* __restrict__ qv,
    __bf16* __restrict__ kk, __bf16* __restrict__ vt,
    __bf16* __restrict__ phZ,
    float* __restrict__ outp)
{
  constexpr int MR = 2;                       // m-frags per wave
  constexpr int BM = MR * 32;                 // 64-row block M-tile
  __shared__ __align__(16) __bf16 smem[BM * 64 + 128 * 64];
  __bf16* As = smem;                 // [64 x 64]
  __bf16* Bs = smem + BM * 64;       // [128 x 64]
  __bf16* trans = smem;              // z=2 epilogue: [128 d][64 s]

  const int bid = blockIdx.x;
  const int u = bid >> 3;
  const int by = u & 3;
  const int idx = (bid & 7) + 8 * (u >> 2);
  int bx, z;
  if (MODE == 0) { bx = idx & 63; z = idx >> 6; }
  else           { bx = idx;      z = 4; }

  const __bf16* Ag = (z < 4) ? (xb + (size_t)z * XN) : ctxp;
  const __bf16* Bg = wb + (size_t)z * WN;

  const int tid = threadIdx.x;
  const int wid = tid >> 6;
  const int ln = tid & 63;
  const int lm = ln & 15, lg = ln >> 4;
  const int wr = wid >> 1, wc = wid & 1;
  const int brow = bx * BM;
  const int bcol = by * 128;

  const int srow = ln >> 3;
  const int sc   = ln & 7;

  f32x4 acc[MR][4] = {};

  for (int kt = 0; kt < DIM / 64; ++kt) {
    const int k0 = kt * 64;
#pragma unroll
    for (int i = 0; i < MR; ++i) {            // A: 64 rows
      const int rb = wid * (MR * 8) + i * 8;
      const int r = rb + srow;
      const int cg = sc ^ (r & 7);
      gload_lds16(Ag + (size_t)(brow + r) * DIM + k0 + cg * 8, &As[rb * 64]);
    }
#pragma unroll
    for (int i = 0; i < 4; ++i) {             // B: 128 rows
      const int rb = wid * 32 + i * 8;
      const int r = rb + srow;
      const int cg = sc ^ (r & 7);
      gload_lds16(Bg + (size_t)(bcol + r) * DIM + k0 + cg * 8, &Bs[rb * 64]);
    }
    __syncthreads();

#pragma unroll
    for (int ks = 0; ks < 2; ++ks) {
      bf16x8 a[MR], b[4];
#pragma unroll
      for (int m = 0; m < MR; ++m) {
        const int row = wr * (MR * 16) + m * 16 + lm;
        const int cc = (ks * 4 + lg) ^ (row & 7);
        a[m] = *(const bf16x8*)&As[row * 64 + cc * 8];
      }
#pragma unroll
      for (int n = 0; n < 4; ++n) {
        const int row = wc * 64 + n * 16 + lm;
        const int cc = (ks * 4 + lg) ^ (row & 7);
        b[n] = *(const bf16x8*)&Bs[row * 64 + cc * 8];
      }
#pragma unroll
      for (int m = 0; m < MR; ++m)
#pragma unroll
        for (int n = 0; n < 4; ++n)
          acc[m][n] = MFMA16(a[m], b[n], acc[m][n]);
    }
    __syncthreads();
  }

  // ---- epilogue
  if (MODE == 0 && z == 2) {
    // k-interleaved V^T via LDS transpose (MR=2 form). Each wave owns a
    // 32-s-block (rows wr*32..wr*32+31); pair (s, s+16) = (acc[0][n][r],
    // acc[1][n][r]) with t = lg*4+r -> slots (2t, 2t+1) at p = wr*32 + 2t.
    const int b = brow >> 10;
    const int sbase = brow & (S - 1);
#pragma unroll
    for (int n = 0; n < 4; ++n) {
      const int dl = wc * 64 + n * 16 + lm;          // 0..127
      const float bias = bv[bcol + dl];
#pragma unroll
      for (int r = 0; r < 4; ++r) {
        const int p = wr * 32 + 2 * (lg * 4 + r);    // even slot
        bf16x2 pk;
        pk[0] = (__bf16)(acc[0][n][r] + bias);       // col s
        pk[1] = (__bf16)(acc[1][n][r] + bias);       // col s+16
        const int base = dl * 64 + (((p >> 3) ^ (dl & 7)) * 8) + (p & 7);
        *(bf16x2*)(trans + base) = pk;
      }
    }
    __syncthreads();
#pragma unroll
    for (int j = 0; j < 2; ++j) {
      const int dl = (tid >> 2) + j * 64;            // 0..127
      const int d = dl & 31, hl = dl >> 5;
      const int cp = (tid & 3) * 2;                  // chunk pair (16 elems)
      bf16x8 v0 = *(const bf16x8*)(trans + dl * 64 + ((cp ^ (dl & 7)) * 8));
      bf16x8 v1 = *(const bf16x8*)(trans + dl * 64 + (((cp + 1) ^ (dl & 7)) * 8));
      const int bh2 = b * H + (bcol >> 5) + hl;
      __bf16* dst = vt + ((size_t)bh2 * Dh + d) * S + sbase + cp * 8;
      *(bf16x8*)dst = v0;
      *(bf16x8*)(dst + 8) = v1;
    }
    return;
  }

#pragma unroll
  for (int n = 0; n < 4; ++n) {
    const int o = bcol + wc * 64 + n * 16 + lm;
    float bias = 0.f, ubv = 0.f, vbv = 0.f;
    if (z == 0) { bias = bq[o]; ubv = ub[o]; vbv = vb[o]; }
    else if (z == 1) bias = bk[o];
    else if (z == 4) bias = bo[o];
    const int h = o >> 5, d = o & 31;
#pragma unroll
    for (int m = 0; m < MR; ++m) {
#pragma unroll
      for (int r = 0; r < 4; ++r) {
        const int M = brow + wr * (MR * 16) + m * 16 + lg * 4 + r;
        const float val = acc[m][n][r];
        if (z == 4) {
          outp[(size_t)M * DIM + o] = val + bias;
          continue;
        }
        const int b = M >> 10, s = M & (S - 1);
        const int bh = b * H + h;
        if (z == 0) {
          // 1/sqrt(Dh)*log2(e) folded in (scores feed v_exp_f32 directly).
          const size_t idx2 = ((size_t)bh * S + s) * Dh + d;
          qu[idx2] = (__bf16)((val + bias + ubv) * SCALEL2E);
          qv[idx2] = (__bf16)((val + bias + vbv) * SCALEL2E);
        } else if (z == 1) {
          kk[((size_t)bh * S + s) * Dh + d] = (__bf16)(val + bias);
        } else {
          // phZ rows [S+1, 2S+1) = p; zero bands pre-filled by conv.
          phZ[((size_t)bh * ZROWS + (S + 1 + s)) * Dh + d] = (__bf16)val;
        }
      }
    }
  }
}

// ---------------------------------------------------------------------------
// Kernel 2: fused attention (R16, unchanged). 256-thread blocks, 4 waves x
// 16 q-rows, grid 1024. K/V staged 2 64-k groups ahead in 4 LDS buffers with
// 2-way-free XOR swizzle s(row)=(row>>1)&3; Z windows register-reused (4
// loads/iter); ONE barrier per 64-k with counted vmcnt(3); per-half P
// buffers (packed b32 stores, k-interleaved V^T); setprio around MFMA;
// ones-MFMA row sums; max-free softmax (exp2); pos gather via __shfl.
// ---------------------------------------------------------------------------
__global__ __launch_bounds__(256, 4) void attn_kernel(
    const __bf16* __restrict__ qu, const __bf16* __restrict__ qv,
    const __bf16* __restrict__ kk, const __bf16* __restrict__ vt,
    const __bf16* __restrict__ phZ,
    __bf16* __restrict__ ctx)
{
  __shared__ __align__(16) __bf16 kv_lds[4][2][1024];  // [buf][K|V][32x32]
  __shared__ __align__(16) __bf16 at_all[4][2][16 * 40];

  const int tid = threadIdx.x;
  const int wid = tid >> 6;
  const int l = tid & 63;
  const int lm = l & 15, lg = l >> 4;

  const int bid = blockIdx.x;               // [0, 1024)
  const int bh = (bid & 7) + 8 * ((bid >> 3) & 7);  // bh resident on XCD bid&7
  const int q0 = (bid >> 6) * 64 + wid * 16;
  const int h = bh & (H - 1), b = bh >> 4;

  const __bf16* qub = qu + (size_t)bh * S * Dh;
  const __bf16* qvb = qv + (size_t)bh * S * Dh;
  const __bf16* kb  = kk + (size_t)bh * S * Dh;
  const __bf16* vtb = vt + (size_t)bh * Dh * S;
  const __bf16* pZb = phZ + (size_t)bh * ZROWS * Dh;
  const __bf16* pAb = pZb + (size_t)(S + 1) * Dh;   // pA[m] = Z[S+1+m]

  const bf16x8 au  = *(const bf16x8*)(qub + (size_t)(q0 + lm) * Dh + lg * 8);
  const bf16x8 avA = *(const bf16x8*)(qvb + (size_t)(q0 + lm) * Dh + lg * 8);
  // row q+1 for the pB term; one-past reads hit allocated memory and are
  // multiplied by pB rows that are exactly zero wherever consumed.
  const bf16x8 avB = *(const bf16x8*)(qvb + (size_t)(q0 + 1 + lm) * Dh + lg * 8);

  int  slr[4];
  bool prd[4];
#pragma unroll
  for (int r = 0; r < 4; ++r) {
    const int qr = lg * 4 + r;
    slr[r] = (l & 48) | ((lm - qr + 15) & 15);
    prd[r] = (lm <= qr);
  }

  bf16x8 ones8;
#pragma unroll
  for (int i = 0; i < 8; ++i) ones8[i] = (__bf16)1.0f;

  f32x4 cta = {0.f,0.f,0.f,0.f}, ctb = {0.f,0.f,0.f,0.f};
  f32x4 ls  = {0.f,0.f,0.f,0.f};
  const f32x4 zero4 = {0.f,0.f,0.f,0.f};

  // staging: lane l writes 16B at linear offset l*16 in its wave's 1KB
  // quadrant (rows srow=l>>2, storage chunk l&3). Source chunk inverse-
  // swizzled with s(row) = (row>>1)&3  ->  ((l&3) ^ ((l>>3)&3)).
  const int srow = l >> 2;
  const int scg  = ((l & 3) ^ ((l >> 3) & 3)) * 8;
  auto stage = [&](int kt, int buf) {
    const __bf16* src;
    if (wid == 0)      src = kb  + (size_t)(kt + srow) * Dh + scg;
    else if (wid == 1) src = kb  + (size_t)(kt + 16 + srow) * Dh + scg;
    else if (wid == 2) src = vtb + (size_t)srow * S + kt + scg;
    else               src = vtb + (size_t)(16 + srow) * S + kt + scg;
    gload_lds16(src, &kv_lds[buf][wid >> 1][(wid & 1) * 512]);
  };

  // read chunk, same swizzle: rows lm and lm+16 share s = (lm>>1)&3.
  const int cc = (lg ^ ((lm >> 1) & 3)) * 8;

  // Z-window tile load: window(ktc) tile at +off (16-row tile), base uB_.
  auto zld = [&](int ktc, int off, bool uB_) -> bf16x8 {
    const int mb = ktc - q0 + (S - 16);
    const __bf16* zb = uB_ ? pZb : pAb;
    return *(const bf16x8*)(zb + (size_t)(mb + off + lm) * Dh + lg * 8);
  };

  // One 32-k tile using a resident Z register set.
  auto half = [&](int kt, int tb, __bf16* at,
                  bf16x8 z0, bf16x8 z1, bf16x8 z2, bool uB_) {
    const __bf16* Ks = kv_lds[tb][0];
    const __bf16* Vs = kv_lds[tb][1];
    bf16x8 kf0 = *(const bf16x8*)(Ks + lm * 32 + cc);
    bf16x8 kf1 = *(const bf16x8*)(Ks + (lm + 16) * 32 + cc);
    __builtin_amdgcn_s_setprio(1);
    f32x4 c0 = MFMA16(au, kf0, zero4);
    f32x4 c1 = MFMA16(au, kf1, zero4);
    const bf16x8 av = uB_ ? avB : avA;
    f32x4 pt0 = MFMA16(av, z0, zero4);
    f32x4 pt1 = MFMA16(av, z1, zero4);
    f32x4 pt2 = MFMA16(av, z2, zero4);
    __builtin_amdgcn_s_setprio(0);
    if (uB_ && (kt < q0 + 16)) {  // diagonal band (once per wave): add pA term
      const int mb = kt - q0 + (S - 16);
      bf16x8 y0 = *(const bf16x8*)(pAb + (size_t)(mb + lm) * Dh + lg * 8);
      bf16x8 y1 = *(const bf16x8*)(pAb + (size_t)(mb + 16 + lm) * Dh + lg * 8);
      bf16x8 y2 = *(const bf16x8*)(pAb + (size_t)(mb + 32 + lm) * Dh + lg * 8);
      pt0 = MFMA16(avA, y0, pt0);
      pt1 = MFMA16(avA, y1, pt1);
      pt2 = MFMA16(avA, y2, pt2);
    }

#pragma unroll
    for (int r = 0; r < 4; ++r) {
      const float v0 = __shfl(pt0[r], slr[r], 64);
      const float v1 = __shfl(pt1[r], slr[r], 64);
      const float v2 = __shfl(pt2[r], slr[r], 64);
      const float s0 = c0[r] + (prd[r] ? v0 : v1);
      const float s1 = c1[r] + (prd[r] ? v1 : v2);
      bf16x2 pp;
      pp[0] = (__bf16)fexp2(s0);             // k-col kt+lm     -> slot 2*lm
      pp[1] = (__bf16)fexp2(s1);             // k-col kt+16+lm  -> slot 2*lm+1
      *(bf16x2*)(at + (lg * 4 + r) * 40 + 2 * lm) = pp;
    }

    bf16x8 af  = *(const bf16x8*)(at + lm * 40 + lg * 8);
    bf16x8 vf0 = *(const bf16x8*)(Vs + lm * 32 + cc);
    bf16x8 vf1 = *(const bf16x8*)(Vs + (lm + 16) * 32 + cc);
    __builtin_amdgcn_s_setprio(1);
    cta = MFMA16(af, vf0, cta);
    ctb = MFMA16(af, vf1, ctb);
    ls  = MFMA16(af, ones8, ls);
    __builtin_amdgcn_s_setprio(0);
  };

  __bf16* at0 = at_all[wid][0];
  __bf16* at1 = at_all[wid][1];

  // ---- prologue: Z(0) + stage tiles 0,1.
  bf16x8 zA0, zA1, zA2;
  bool uA = (0 > q0 - 31);
  zA0 = zld(0, 0, uA);
  zA1 = zld(0, 16, uA);
  zA2 = zld(0, 32, uA);
  stage(0, 0);
  stage(32, 1);
  asm volatile("s_waitcnt vmcnt(0)" ::: "memory");
  __builtin_amdgcn_s_barrier();

  for (int kt = 0; kt < S; kt += 64) {
    const int t = kt >> 5;
    // next-64k stages first (oldest in vmcnt order -> full-body slack)
    stage((kt + 64 < S) ? kt + 64 : kt, (t + 2) & 3);
    stage((kt + 96 < S) ? kt + 96 : kt, (t + 3) & 3);

    // zB window (kt+32): tile0 == zA window tile2 when bases match.
    const bool uB = ((kt + 32) > q0 - 31);
    bf16x8 zB0;
    if (uB == uA) zB0 = zA2;
    else          zB0 = zld(kt + 32, 0, uB);
    bf16x8 zB1 = zld(kt + 32, 16, uB);
    bf16x8 zB2 = zld(kt + 32, 32, uB);

    half(kt, t & 3, at0, zA0, zA1, zA2, uA);

    // zA' window (kt+64): tiles 16,32 loaded directly (first use next iter);
    // tile0 == zB2 when bases match (copied after half B).
    const int ktn = (kt + 64 < S) ? kt + 64 : (S - 32);
    const bool uAn = (ktn > q0 - 31);
    zA1 = zld(ktn, 16, uAn);
    zA2 = zld(ktn, 32, uAn);

    half(kt + 32, (t + 1) & 3, at1, zB0, zB1, zB2, uB);

    if (uAn == uB) zA0 = zB2;
    else           zA0 = zld(ktn, 0, uAn);
    uA = uAn;

    asm volatile("s_waitcnt vmcnt(3)" ::: "memory");
    __builtin_amdgcn_s_barrier();
  }

  // ---- normalize + store ctx (ls[r] = row sum, identical across lm lanes)
#pragma unroll
  for (int r = 0; r < 4; ++r) {
    const int s0 = q0 + lg * 4 + r;
    const float inv = 1.f / ls[r];
    __bf16* cp = ctx + ((size_t)b * S + s0) * DIM + h * Dh;
    cp[lm]      = (__bf16)(cta[r] * inv);
    cp[16 + lm] = (__bf16)(ctb[r] * inv);
  }
}

// ---------------------------------------------------------------------------
extern "C" void kernel_launch(void* const* d_in, const int* in_sizes, int n_in,
                              void* d_out, int out_size, void* d_ws, size_t ws_size,
                              hipStream_t stream) {
  const float* query = (const float*)d_in[0];
  const float* key   = (const float*)d_in[1];
  const float* value = (const float*)d_in[2];
  const float* pos   = (const float*)d_in[3];
  const float* Wq = (const float*)d_in[4];
  const float* bq = (const float*)d_in[5];
  const float* Wk = (const float*)d_in[6];
  const float* bk = (const float*)d_in[7];
  const float* Wv = (const float*)d_in[8];
  const float* bv = (const float*)d_in[9];
  const float* Wp = (const float*)d_in[10];
  const float* ub = (const float*)d_in[11];
  const float* vb = (const float*)d_in[12];
  const float* Wo = (const float*)d_in[13];
  const float* bo = (const float*)d_in[14];
  float* out = (float*)d_out;

  char* ws = (char*)d_ws;
  const size_t MB = 1ull << 20;
  // Layout:
  //   [ 0,16) MB : xb (4x bf16 activations)
  //   [16,18.5)  : wb (5x bf16 weights)
  //   [19,23)    : qu   [23,27): qv   [27,31): kk   [31,35): vt
  //   [35,47.7)  : phZ [B*H, 3S+16, 32]
  //   [48,52)    : ctx bf16
  __bf16* xb  = (__bf16*)(ws + 0 * MB);
  __bf16* wb  = (__bf16*)(ws + 16 * MB);
  __bf16* qu  = (__bf16*)(ws + 19 * MB);
  __bf16* qv  = (__bf16*)(ws + 23 * MB);
  __bf16* kk  = (__bf16*)(ws + 27 * MB);
  __bf16* vt  = (__bf16*)(ws + 31 * MB);
  __bf16* phZ = (__bf16*)(ws + 35 * MB);
  __bf16* ctx = (__bf16*)(ws + 48 * MB);

  conv_kernel<<<dim3(1024, 10), dim3(256), 0, stream>>>(
      query, key, value, pos, Wq, Wk, Wv, Wp, Wo, xb, wb, phZ);

  gemm_kernel<0><<<dim3(1024), dim3(256), 0, stream>>>(
      xb, wb, ctx, bq, bk, bv, bo, ub, vb,
      qu, qv, kk, vt, phZ, out);

  attn_kernel<<<dim3(1024), dim3(256), 0, stream>>>(
      qu, qv, kk, vt, phZ, ctx);

  gemm_kernel<1><<<dim3(256), dim3(256), 0, stream>>>(
      xb, wb, ctx, bq, bk, bv, bo, ub, vb,
      qu, qv, kk, vt, phZ, out);
}

// Round 18
// 77.276 us; speedup vs baseline: 1.3443x; 1.0629x over previous
//
#include <hip/hip_runtime.h>
#include <hip/hip_bf16.h>
#include <math.h>

// Transformer-XL relative multi-head attention, bf16 MFMA implementation.
// B=4, S=1024, H=16, Dh=32, DIM=512.
//
// relative_shift identity: shifted[q,k] = qv[q]·pA[m] + qv[q+1]·pB[m],
// m = k - q + S - 1;  pA[m]=Z[S+1+m], pB[m]=Z[m] with a single zero-padded
// tensor Z (rows [S+1, 2S+1) = p, all else 0).
//
// Round 18: activation f32->bf16 conversion fused into gemm0's A-staging
// (reg-staging: 2x dwordx4 -> cvt8 -> swizzled ds_write_b128; B stays
// global_load_lds). Kills the xb roundtrip (~32 MB HBM: conv 32R+16W,
// gemm 16R -> gemm 32R once, col-block re-reads are L2 hits via the
// by-fastest XCD-co-located bid mapping). conv shrinks to weights + phZ
// bands (~3 MB). attn (R16) and outproj unchanged.

typedef float f32x4 __attribute__((ext_vector_type(4)));
typedef __bf16 bf16x8 __attribute__((ext_vector_type(8)));
typedef __bf16 bf16x2 __attribute__((ext_vector_type(2)));

#define MFMA16(a, b, c) __builtin_amdgcn_mfma_f32_16x16x32_bf16((a), (b), (c), 0, 0, 0)

constexpr int Bb  = 4;
constexpr int S   = 1024;
constexpr int H   = 16;
constexpr int Dh  = 32;
constexpr int DIM = 512;
// 1/sqrt(32) * log2(e): scores come out pre-scaled for v_exp_f32 (=2^x).
constexpr float SCALEL2E = 0.25501818637084186f;
constexpr int ZROWS = 3 * S + 16;              // phZ rows per (b,h)

constexpr size_t XN = (size_t)Bb * S * DIM;   // elems per activation tensor
constexpr size_t WN = (size_t)DIM * DIM;      // elems per weight matrix

__device__ inline bf16x8 cvt8(const float* __restrict__ p) {
  f32x4 a = *(const f32x4*)p;
  f32x4 b = *(const f32x4*)(p + 4);
  bf16x8 r;
  r[0] = (__bf16)a[0]; r[1] = (__bf16)a[1]; r[2] = (__bf16)a[2]; r[3] = (__bf16)a[3];
  r[4] = (__bf16)b[0]; r[5] = (__bf16)b[1]; r[6] = (__bf16)b[2]; r[7] = (__bf16)b[3];
  return r;
}

__device__ inline float fexp2(float x) {
  float r;
  asm("v_exp_f32 %0, %1" : "=v"(r) : "v"(x));
  return r;
}

__device__ inline void gload_lds16(const __bf16* g, __bf16* l) {
  __builtin_amdgcn_global_load_lds(
      (const __attribute__((address_space(1))) unsigned int*)g,
      (__attribute__((address_space(3))) unsigned int*)l, 16, 0, 0);
}

// ---------------------------------------------------------------------------
// Kernel 0: f32 -> bf16 weight conversion (y=0..4) + phZ zero bands (y=5).
// ---------------------------------------------------------------------------
__global__ __launch_bounds__(256) void conv_kernel(
    const float* __restrict__ wq, const float* __restrict__ wk,
    const float* __restrict__ wv, const float* __restrict__ wp,
    const float* __restrict__ wo,
    __bf16* __restrict__ wb, __bf16* __restrict__ phZ)
{
  const int y = blockIdx.y;
  if (y == 5) {
    // zero only the bands the attn kernel ever reads as zeros:
    // rows [960,1032) and [2040,2104) per bh (p rows overwrite the overlap).
    const int e8 = blockIdx.x * 256 + threadIdx.x;   // grid.x = 136
    if (e8 < 64 * 136 * 4) {
      const int rowIdx = e8 >> 2, chunk = e8 & 3;
      const int bh = rowIdx / 136;
      const int rl = rowIdx - bh * 136;
      const int row = (rl < 72) ? (960 + rl) : (2040 + (rl - 72));
      bf16x8 zz = {};
      *(bf16x8*)(phZ + ((size_t)bh * ZROWS + row) * Dh + chunk * 8) = zz;
    }
    return;
  }
  const float* src = (y == 0) ? wq : (y == 1) ? wk : (y == 2) ? wv
                   : (y == 3) ? wp : wo;
  __bf16* dst = wb + (size_t)y * WN;
  const size_t i = ((size_t)blockIdx.x * 256 + threadIdx.x) * 8;
  if (i >= WN) return;
  *(bf16x8*)(dst + i) = cvt8(src + i);
}

// ---------------------------------------------------------------------------
// Kernel 1: tiled bf16 GEMM  C[M, N=512] = A @ B^T, K=512.
// BM=64 (MR=2), 4 waves, BK=64; B via global_load_lds(16B, XOR-swizzled
// source). MODE 0 (z=0..3 projections, grid 1024): A staged from the f32
// activation inputs with inline cvt (reg-staging + swizzled ds_write_b128).
// MODE 1 (z=4 outproj, grid 256): A = ctx bf16 via global_load_lds.
// z=2 writes k-interleaved V^T via LDS transpose (packed bf16x2 writes +
// coalesced b128 global stores).
// ---------------------------------------------------------------------------
template <int MODE>
__global__ __launch_bounds__(256) void gemm_kernel(
    const float* __restrict__ xq, const float* __restrict__ xk,
    const float* __restrict__ xv, const float* __restrict__ xp,
    const __bf16* __restrict__ wb, const __bf16* __restrict__ ctxp,
    const float* __restrict__ bq, const float* __restrict__ bk,
    const float* __restrict__ bv, const float* __restrict__ bo,
    const float* __restrict__ ub, const float* __restrict__ vb,
    __bf16* __restrict__ qu, __bf16* __restrict__ qv,
    __bf16* __restrict__ kk, __bf16* __restrict__ vt,
    __bf16* __restrict__ phZ,
    float* __restrict__ outp)
{
  constexpr int MR = 2;                       // m-frags per wave
  constexpr int BM = MR * 32;                 // 64-row block M-tile
  __shared__ __align__(16) __bf16 smem[BM * 64 + 128 * 64];
  __bf16* As = smem;                 // [64 x 64]
  __bf16* Bs = smem + BM * 64;       // [128 x 64]
  __bf16* trans = smem;              // z=2 epilogue: [128 d][64 s]

  const int bid = blockIdx.x;
  const int u = bid >> 3;
  const int by = u & 3;
  const int idx = (bid & 7) + 8 * (u >> 2);
  int bx, z;
  if (MODE == 0) { bx = idx & 63; z = idx >> 6; }
  else           { bx = idx;      z = 4; }

  const float* Axf = (z == 0) ? xq : (z == 1) ? xk : (z == 2) ? xv : xp;
  const __bf16* Bg = wb + (size_t)z * WN;

  const int tid = threadIdx.x;
  const int wid = tid >> 6;
  const int ln = tid & 63;
  const int lm = ln & 15, lg = ln >> 4;
  const int wr = wid >> 1, wc = wid & 1;
  const int brow = bx * BM;
  const int bcol = by * 128;

  const int srow = ln >> 3;
  const int sc   = ln & 7;

  f32x4 acc[MR][4] = {};

  for (int kt = 0; kt < DIM / 64; ++kt) {
    const int k0 = kt * 64;
    if (MODE == 0) {
      // A: f32 -> bf16 reg-staging. Wave stages rows [wid*16, wid*16+16);
      // lane: row rl = wid*16 + (ln>>2), chunks (ln&3) and (ln&3)+4.
      const int rl = wid * 16 + (ln >> 2);
      const float* Af = Axf + (size_t)(brow + rl) * DIM + k0;
      const int c0_ = ln & 3;
      const int c1_ = c0_ + 4;
      *(bf16x8*)&As[rl * 64 + ((c0_ ^ (rl & 7)) * 8)] = cvt8(Af + c0_ * 8);
      *(bf16x8*)&As[rl * 64 + ((c1_ ^ (rl & 7)) * 8)] = cvt8(Af + c1_ * 8);
    } else {
#pragma unroll
      for (int i = 0; i < MR; ++i) {          // A: ctx bf16 via gload_lds
        const int rb = wid * (MR * 8) + i * 8;
        const int r = rb + srow;
        const int cg = sc ^ (r & 7);
        gload_lds16(ctxp + (size_t)(brow + r) * DIM + k0 + cg * 8,
                    &As[rb * 64]);
      }
    }
#pragma unroll
    for (int i = 0; i < 4; ++i) {             // B: 128 rows via gload_lds
      const int rb = wid * 32 + i * 8;
      const int r = rb + srow;
      const int cg = sc ^ (r & 7);
      gload_lds16(Bg + (size_t)(bcol + r) * DIM + k0 + cg * 8, &Bs[rb * 64]);
    }
    __syncthreads();

#pragma unroll
    for (int ks = 0; ks < 2; ++ks) {
      bf16x8 a[MR], b[4];
#pragma unroll
      for (int m = 0; m < MR; ++m) {
        const int row = wr * (MR * 16) + m * 16 + lm;
        const int cc = (ks * 4 + lg) ^ (row & 7);
        a[m] = *(const bf16x8*)&As[row * 64 + cc * 8];
      }
#pragma unroll
      for (int n = 0; n < 4; ++n) {
        const int row = wc * 64 + n * 16 + lm;
        const int cc = (ks * 4 + lg) ^ (row & 7);
        b[n] = *(const bf16x8*)&Bs[row * 64 + cc * 8];
      }
#pragma unroll
      for (int m = 0; m < MR; ++m)
#pragma unroll
        for (int n = 0; n < 4; ++n)
          acc[m][n] = MFMA16(a[m], b[n], acc[m][n]);
    }
    __syncthreads();
  }

  // ---- epilogue
  if (MODE == 0 && z == 2) {
    // k-interleaved V^T via LDS transpose (MR=2 form). Each wave owns a
    // 32-s-block (rows wr*32..wr*32+31); pair (s, s+16) = (acc[0][n][r],
    // acc[1][n][r]) with t = lg*4+r -> slots (2t, 2t+1) at p = wr*32 + 2t.
    const int b = brow >> 10;
    const int sbase = brow & (S - 1);
#pragma unroll
    for (int n = 0; n < 4; ++n) {
      const int dl = wc * 64 + n * 16 + lm;          // 0..127
      const float bias = bv[bcol + dl];
#pragma unroll
      for (int r = 0; r < 4; ++r) {
        const int p = wr * 32 + 2 * (lg * 4 + r);    // even slot
        bf16x2 pk;
        pk[0] = (__bf16)(acc[0][n][r] + bias);       // col s
        pk[1] = (__bf16)(acc[1][n][r] + bias);       // col s+16
        const int base = dl * 64 + (((p >> 3) ^ (dl & 7)) * 8) + (p & 7);
        *(bf16x2*)(trans + base) = pk;
      }
    }
    __syncthreads();
#pragma unroll
    for (int j = 0; j < 2; ++j) {
      const int dl = (tid >> 2) + j * 64;            // 0..127
      const int d = dl & 31, hl = dl >> 5;
      const int cp = (tid & 3) * 2;                  // chunk pair (16 elems)
      bf16x8 v0 = *(const bf16x8*)(trans + dl * 64 + ((cp ^ (dl & 7)) * 8));
      bf16x8 v1 = *(const bf16x8*)(trans + dl * 64 + (((cp + 1) ^ (dl & 7)) * 8));
      const int bh2 = b * H + (bcol >> 5) + hl;
      __bf16* dst = vt + ((size_t)bh2 * Dh + d) * S + sbase + cp * 8;
      *(bf16x8*)dst = v0;
      *(bf16x8*)(dst + 8) = v1;
    }
    return;
  }

#pragma unroll
  for (int n = 0; n < 4; ++n) {
    const int o = bcol + wc * 64 + n * 16 + lm;
    float bias = 0.f, ubv = 0.f, vbv = 0.f;
    if (z == 0) { bias = bq[o]; ubv = ub[o]; vbv = vb[o]; }
    else if (z == 1) bias = bk[o];
    else if (z == 4) bias = bo[o];
    const int h = o >> 5, d = o & 31;
#pragma unroll
    for (int m = 0; m < MR; ++m) {
#pragma unroll
      for (int r = 0; r < 4; ++r) {
        const int M = brow + wr * (MR * 16) + m * 16 + lg * 4 + r;
        const float val = acc[m][n][r];
        if (z == 4) {
          outp[(size_t)M * DIM + o] = val + bias;
          continue;
        }
        const int b = M >> 10, s = M & (S - 1);
        const int bh = b * H + h;
        if (z == 0) {
          // 1/sqrt(Dh)*log2(e) folded in (scores feed v_exp_f32 directly).
          const size_t idx2 = ((size_t)bh * S + s) * Dh + d;
          qu[idx2] = (__bf16)((val + bias + ubv) * SCALEL2E);
          qv[idx2] = (__bf16)((val + bias + vbv) * SCALEL2E);
        } else if (z == 1) {
          kk[((size_t)bh * S + s) * Dh + d] = (__bf16)(val + bias);
        } else {
          // phZ rows [S+1, 2S+1) = p; zero bands pre-filled by conv.
          phZ[((size_t)bh * ZROWS + (S + 1 + s)) * Dh + d] = (__bf16)val;
        }
      }
    }
  }
}

// ---------------------------------------------------------------------------
// Kernel 2: fused attention (R16, unchanged). 256-thread blocks, 4 waves x
// 16 q-rows, grid 1024. K/V staged 2 64-k groups ahead in 4 LDS buffers with
// 2-way-free XOR swizzle s(row)=(row>>1)&3; Z windows register-reused (4
// loads/iter); ONE barrier per 64-k with counted vmcnt(3); per-half P
// buffers (packed b32 stores, k-interleaved V^T); setprio around MFMA;
// ones-MFMA row sums; max-free softmax (exp2); pos gather via __shfl.
// ---------------------------------------------------------------------------
__global__ __launch_bounds__(256, 4) void attn_kernel(
    const __bf16* __restrict__ qu, const __bf16* __restrict__ qv,
    const __bf16* __restrict__ kk, const __bf16* __restrict__ vt,
    const __bf16* __restrict__ phZ,
    __bf16* __restrict__ ctx)
{
  __shared__ __align__(16) __bf16 kv_lds[4][2][1024];  // [buf][K|V][32x32]
  __shared__ __align__(16) __bf16 at_all[4][2][16 * 40];

  const int tid = threadIdx.x;
  const int wid = tid >> 6;
  const int l = tid & 63;
  const int lm = l & 15, lg = l >> 4;

  const int bid = blockIdx.x;               // [0, 1024)
  const int bh = (bid & 7) + 8 * ((bid >> 3) & 7);  // bh resident on XCD bid&7
  const int q0 = (bid >> 6) * 64 + wid * 16;
  const int h = bh & (H - 1), b = bh >> 4;

  const __bf16* qub = qu + (size_t)bh * S * Dh;
  const __bf16* qvb = qv + (size_t)bh * S * Dh;
  const __bf16* kb  = kk + (size_t)bh * S * Dh;
  const __bf16* vtb = vt + (size_t)bh * Dh * S;
  const __bf16* pZb = phZ + (size_t)bh * ZROWS * Dh;
  const __bf16* pAb = pZb + (size_t)(S + 1) * Dh;   // pA[m] = Z[S+1+m]

  const bf16x8 au  = *(const bf16x8*)(qub + (size_t)(q0 + lm) * Dh + lg * 8);
  const bf16x8 avA = *(const bf16x8*)(qvb + (size_t)(q0 + lm) * Dh + lg * 8);
  // row q+1 for the pB term; one-past reads hit allocated memory and are
  // multiplied by pB rows that are exactly zero wherever consumed.
  const bf16x8 avB = *(const bf16x8*)(qvb + (size_t)(q0 + 1 + lm) * Dh + lg * 8);

  int  slr[4];
  bool prd[4];
#pragma unroll
  for (int r = 0; r < 4; ++r) {
    const int qr = lg * 4 + r;
    slr[r] = (l & 48) | ((lm - qr + 15) & 15);
    prd[r] = (lm <= qr);
  }

  bf16x8 ones8;
#pragma unroll
  for (int i = 0; i < 8; ++i) ones8[i] = (__bf16)1.0f;

  f32x4 cta = {0.f,0.f,0.f,0.f}, ctb = {0.f,0.f,0.f,0.f};
  f32x4 ls  = {0.f,0.f,0.f,0.f};
  const f32x4 zero4 = {0.f,0.f,0.f,0.f};

  // staging: lane l writes 16B at linear offset l*16 in its wave's 1KB
  // quadrant (rows srow=l>>2, storage chunk l&3). Source chunk inverse-
  // swizzled with s(row) = (row>>1)&3  ->  ((l&3) ^ ((l>>3)&3)).
  const int srow = l >> 2;
  const int scg  = ((l & 3) ^ ((l >> 3) & 3)) * 8;
  auto stage = [&](int kt, int buf) {
    const __bf16* src;
    if (wid == 0)      src = kb  + (size_t)(kt + srow) * Dh + scg;
    else if (wid == 1) src = kb  + (size_t)(kt + 16 + srow) * Dh + scg;
    else if (wid == 2) src = vtb + (size_t)srow * S + kt + scg;
    else               src = vtb + (size_t)(16 + srow) * S + kt + scg;
    gload_lds16(src, &kv_lds[buf][wid >> 1][(wid & 1) * 512]);
  };

  // read chunk, same swizzle: rows lm and lm+16 share s = (lm>>1)&3.
  const int cc = (lg ^ ((lm >> 1) & 3)) * 8;

  // Z-window tile load: window(ktc) tile at +off (16-row tile), base uB_.
  auto zld = [&](int ktc, int off, bool uB_) -> bf16x8 {
    const int mb = ktc - q0 + (S - 16);
    const __bf16* zb = uB_ ? pZb : pAb;
    return *(const bf16x8*)(zb + (size_t)(mb + off + lm) * Dh + lg * 8);
  };

  // One 32-k tile using a resident Z register set.
  auto half = [&](int kt, int tb, __bf16* at,
                  bf16x8 z0, bf16x8 z1, bf16x8 z2, bool uB_) {
    const __bf16* Ks = kv_lds[tb][0];
    const __bf16* Vs = kv_lds[tb][1];
    bf16x8 kf0 = *(const bf16x8*)(Ks + lm * 32 + cc);
    bf16x8 kf1 = *(const bf16x8*)(Ks + (lm + 16) * 32 + cc);
    __builtin_amdgcn_s_setprio(1);
    f32x4 c0 = MFMA16(au, kf0, zero4);
    f32x4 c1 = MFMA16(au, kf1, zero4);
    const bf16x8 av = uB_ ? avB : avA;
    f32x4 pt0 = MFMA16(av, z0, zero4);
    f32x4 pt1 = MFMA16(av, z1, zero4);
    f32x4 pt2 = MFMA16(av, z2, zero4);
    __builtin_amdgcn_s_setprio(0);
    if (uB_ && (kt < q0 + 16)) {  // diagonal band (once per wave): add pA term
      const int mb = kt - q0 + (S - 16);
      bf16x8 y0 = *(const bf16x8*)(pAb + (size_t)(mb + lm) * Dh + lg * 8);
      bf16x8 y1 = *(const bf16x8*)(pAb + (size_t)(mb + 16 + lm) * Dh + lg * 8);
      bf16x8 y2 = *(const bf16x8*)(pAb + (size_t)(mb + 32 + lm) * Dh + lg * 8);
      pt0 = MFMA16(avA, y0, pt0);
      pt1 = MFMA16(avA, y1, pt1);
      pt2 = MFMA16(avA, y2, pt2);
    }

#pragma unroll
    for (int r = 0; r < 4; ++r) {
      const float v0 = __shfl(pt0[r], slr[r], 64);
      const float v1 = __shfl(pt1[r], slr[r], 64);
      const float v2 = __shfl(pt2[r], slr[r], 64);
      const float s0 = c0[r] + (prd[r] ? v0 : v1);
      const float s1 = c1[r] + (prd[r] ? v1 : v2);
      bf16x2 pp;
      pp[0] = (__bf16)fexp2(s0);             // k-col kt+lm     -> slot 2*lm
      pp[1] = (__bf16)fexp2(s1);             // k-col kt+16+lm  -> slot 2*lm+1
      *(bf16x2*)(at + (lg * 4 + r) * 40 + 2 * lm) = pp;
    }

    bf16x8 af  = *(const bf16x8*)(at + lm * 40 + lg * 8);
    bf16x8 vf0 = *(const bf16x8*)(Vs + lm * 32 + cc);
    bf16x8 vf1 = *(const bf16x8*)(Vs + (lm + 16) * 32 + cc);
    __builtin_amdgcn_s_setprio(1);
    cta = MFMA16(af, vf0, cta);
    ctb = MFMA16(af, vf1, ctb);
    ls  = MFMA16(af, ones8, ls);
    __builtin_amdgcn_s_setprio(0);
  };

  __bf16* at0 = at_all[wid][0];
  __bf16* at1 = at_all[wid][1];

  // ---- prologue: Z(0) + stage tiles 0,1.
  bf16x8 zA0, zA1, zA2;
  bool uA = (0 > q0 - 31);
  zA0 = zld(0, 0, uA);
  zA1 = zld(0, 16, uA);
  zA2 = zld(0, 32, uA);
  stage(0, 0);
  stage(32, 1);
  asm volatile("s_waitcnt vmcnt(0)" ::: "memory");
  __builtin_amdgcn_s_barrier();

  for (int kt = 0; kt < S; kt += 64) {
    const int t = kt >> 5;
    // next-64k stages first (oldest in vmcnt order -> full-body slack)
    stage((kt + 64 < S) ? kt + 64 : kt, (t + 2) & 3);
    stage((kt + 96 < S) ? kt + 96 : kt, (t + 3) & 3);

    // zB window (kt+32): tile0 == zA window tile2 when bases match.
    const bool uB = ((kt + 32) > q0 - 31);
    bf16x8 zB0;
    if (uB == uA) zB0 = zA2;
    else          zB0 = zld(kt + 32, 0, uB);
    bf16x8 zB1 = zld(kt + 32, 16, uB);
    bf16x8 zB2 = zld(kt + 32, 32, uB);

    half(kt, t & 3, at0, zA0, zA1, zA2, uA);

    // zA' window (kt+64): tiles 16,32 loaded directly (first use next iter);
    // tile0 == zB2 when bases match (copied after half B).
    const int ktn = (kt + 64 < S) ? kt + 64 : (S - 32);
    const bool uAn = (ktn > q0 - 31);
    zA1 = zld(ktn, 16, uAn);
    zA2 = zld(ktn, 32, uAn);

    half(kt + 32, (t + 1) & 3, at1, zB0, zB1, zB2, uB);

    if (uAn == uB) zA0 = zB2;
    else           zA0 = zld(ktn, 0, uAn);
    uA = uAn;

    asm volatile("s_waitcnt vmcnt(3)" ::: "memory");
    __builtin_amdgcn_s_barrier();
  }

  // ---- normalize + store ctx (ls[r] = row sum, identical across lm lanes)
#pragma unroll
  for (int r = 0; r < 4; ++r) {
    const int s0 = q0 + lg * 4 + r;
    const float inv = 1.f / ls[r];
    __bf16* cp = ctx + ((size_t)b * S + s0) * DIM + h * Dh;
    cp[lm]      = (__bf16)(cta[r] * inv);
    cp[16 + lm] = (__bf16)(ctb[r] * inv);
  }
}

// ---------------------------------------------------------------------------
extern "C" void kernel_launch(void* const* d_in, const int* in_sizes, int n_in,
                              void* d_out, int out_size, void* d_ws, size_t ws_size,
                              hipStream_t stream) {
  const float* query = (const float*)d_in[0];
  const float* key   = (const float*)d_in[1];
  const float* value = (const float*)d_in[2];
  const float* pos   = (const float*)d_in[3];
  const float* Wq = (const float*)d_in[4];
  const float* bq = (const float*)d_in[5];
  const float* Wk = (const float*)d_in[6];
  const float* bk = (const float*)d_in[7];
  const float* Wv = (const float*)d_in[8];
  const float* bv = (const float*)d_in[9];
  const float* Wp = (const float*)d_in[10];
  const float* ub = (const float*)d_in[11];
  const float* vb = (const float*)d_in[12];
  const float* Wo = (const float*)d_in[13];
  const float* bo = (const float*)d_in[14];
  float* out = (float*)d_out;

  char* ws = (char*)d_ws;
  const size_t MB = 1ull << 20;
  // Layout:
  //   [16,18.5) MB : wb (5x bf16 weights)
  //   [19,23)      : qu   [23,27): qv   [27,31): kk   [31,35): vt
  //   [35,47.7)    : phZ [B*H, 3S+16, 32]
  //   [48,52)      : ctx bf16
  __bf16* wb  = (__bf16*)(ws + 16 * MB);
  __bf16* qu  = (__bf16*)(ws + 19 * MB);
  __bf16* qv  = (__bf16*)(ws + 23 * MB);
  __bf16* kk  = (__bf16*)(ws + 27 * MB);
  __bf16* vt  = (__bf16*)(ws + 31 * MB);
  __bf16* phZ = (__bf16*)(ws + 35 * MB);
  __bf16* ctx = (__bf16*)(ws + 48 * MB);

  conv_kernel<<<dim3(136, 6), dim3(256), 0, stream>>>(
      Wq, Wk, Wv, Wp, Wo, wb, phZ);

  gemm_kernel<0><<<dim3(1024), dim3(256), 0, stream>>>(
      query, key, value, pos, wb, ctx, bq, bk, bv, bo, ub, vb,
      qu, qv, kk, vt, phZ, out);

  attn_kernel<<<dim3(1024), dim3(256), 0, stream>>>(
      qu, qv, kk, vt, phZ, ctx);

  gemm_kernel<1><<<dim3(256), dim3(256), 0, stream>>>(
      query, key, value, pos, wb, ctx, bq, bk, bv, bo, ub, vb,
      qu, qv, kk, vt, phZ, out);
}